// Round 3
// baseline (1394.179 us; speedup 1.0000x reference)
//
#include <hip/hip_runtime.h>

#define BS 256

// ---------------- bf16 helpers (fallback Y storage) ----------------
__device__ __forceinline__ unsigned short f2bf(float f) {
    unsigned x = __float_as_uint(f);
    unsigned r = (x + 0x7fffu + ((x >> 16) & 1u)) >> 16;
    return (unsigned short)r;
}
struct alignas(8) us4 { unsigned short x, y, z, w; };

__device__ __forceinline__ float4 ldY4(const float* p) { return *(const float4*)p; }
__device__ __forceinline__ float4 ldY4(const unsigned short* p) {
    us4 s = *(const us4*)p;
    float4 r;
    r.x = __uint_as_float((unsigned)s.x << 16);
    r.y = __uint_as_float((unsigned)s.y << 16);
    r.z = __uint_as_float((unsigned)s.z << 16);
    r.w = __uint_as_float((unsigned)s.w << 16);
    return r;
}
__device__ __forceinline__ void stY24(float* p, const float* r) {
#pragma unroll
    for (int j = 0; j < 24; j += 4)
        *(float4*)(p + j) = make_float4(r[j], r[j + 1], r[j + 2], r[j + 3]);
}
__device__ __forceinline__ void stY24(unsigned short* p, const float* r) {
#pragma unroll
    for (int j = 0; j < 24; j += 4) {
        us4 s{f2bf(r[j]), f2bf(r[j + 1]), f2bf(r[j + 2]), f2bf(r[j + 3])};
        *(us4*)(p + j) = s;
    }
}

// ---- node prep: x16 = relu(relu(x_feat @ lpW + lpb) @ tW + tb) ----
__global__ void prep_kernel(const float* __restrict__ xf,
                            const float* __restrict__ W1, const float* __restrict__ b1,
                            const float* __restrict__ W2, const float* __restrict__ b2,
                            float* __restrict__ x16, int N)
{
    int n = blockIdx.x * blockDim.x + threadIdx.x;
    bool valid = n < N;
    int nn = valid ? n : 0;
    float a[24];
#pragma unroll
    for (int i = 0; i < 24; i += 4)
        *(float4*)(a + i) = *(const float4*)(xf + (size_t)nn * 24 + i);
    float h[32];
#pragma unroll
    for (int j = 0; j < 32; j++) {
        float s = b1[j];
#pragma unroll
        for (int i = 0; i < 24; i++) s = fmaf(a[i], W1[i * 32 + j], s);
        h[j] = fmaxf(s, 0.f);
    }
    if (!valid) return;
#pragma unroll
    for (int j = 0; j < 16; j++) {
        float s = b2[j];
#pragma unroll
        for (int i = 0; i < 32; i++) s = fmaf(h[i], W2[i * 16 + j], s);
        x16[(size_t)n * 16 + j] = fmaxf(s, 0.f);
    }
}

// ---- CSR build ----
__global__ void deg_kernel(const int* __restrict__ dst, int* __restrict__ degi, int E)
{
    int i = blockIdx.x * blockDim.x + threadIdx.x;
    if (i < E) atomicAdd(&degi[dst[i]], 1);
}
__global__ void offsets_kernel(const int* __restrict__ degi, int* __restrict__ offs,
                               int* __restrict__ cur, int* __restrict__ cursor, int N)
{
    int n = blockIdx.x * blockDim.x + threadIdx.x;
    if (n < N) {
        int d = degi[n];
        int o = atomicAdd(cursor, d);
        offs[n] = o;
        cur[n] = o;
    }
}
__global__ void fill_kernel(const int* __restrict__ dst, int* __restrict__ cur,
                            int* __restrict__ eid, int E)
{
    int e = blockIdx.x * blockDim.x + threadIdx.x;
    if (e < E) {
        int p = atomicAdd(&cur[dst[e]], 1);
        eid[p] = e;
    }
}

// ---- per-node Y precompute: Y[n, k, a*8+o] = sum_i x[i]*W[a,k,i*8+o]; slot16 = x@B ----
template <int IN, typename YT>
__global__ __launch_bounds__(BS) void ynode_kernel(const float* __restrict__ x,
                                                   const float* __restrict__ W,  // [3][16][IN*8]
                                                   const float* __restrict__ B,  // [3][IN*8]
                                                   YT* __restrict__ Y, int N)
{
    int n = blockIdx.x * BS + threadIdx.x;
    bool valid = n < N;
    int nn = valid ? n : 0;
    float xv[IN];
#pragma unroll
    for (int i = 0; i < IN; i += 4)
        *(float4*)(xv + i) = *(const float4*)(x + (size_t)nn * IN + i);
    YT* yr = Y + (size_t)nn * 408;

    for (int k = 0; k < 16; k++) {   // rolled: weights s_loaded per iter (uniform)
        float r[24];
#pragma unroll
        for (int j = 0; j < 24; j++) r[j] = 0.f;
        const float* w = W + (size_t)k * (IN * 8);
#pragma unroll
        for (int a = 0; a < 3; a++) {
            const float* wa = w + (size_t)a * (16 * IN * 8);
#pragma unroll
            for (int i = 0; i < IN; i++) {
                float xi = xv[i];
#pragma unroll
                for (int o = 0; o < 8; o++)
                    r[a * 8 + o] = fmaf(xi, wa[i * 8 + o], r[a * 8 + o]);
            }
        }
        if (valid) stY24(yr + k * 24, r);
    }
    // bias slot (k=16): sum_i x[i]*B[a, i*8+o]
    {
        float r[24];
#pragma unroll
        for (int j = 0; j < 24; j++) r[j] = 0.f;
#pragma unroll
        for (int a = 0; a < 3; a++) {
            const float* ba = B + (size_t)a * (IN * 8);
#pragma unroll
            for (int i = 0; i < IN; i++) {
                float xi = xv[i];
#pragma unroll
                for (int o = 0; o < 8; o++)
                    r[a * 8 + o] = fmaf(xi, ba[i * 8 + o], r[a * 8 + o]);
            }
        }
        if (valid) stY24(yr + 16 * 24, r);
    }
}

// ---- per-edge: trunk -> er[16] in regs; msg = sum_k er[k]*Y[src,k,:] + Y[src,16,:] ----
template <typename YT>
__global__ __launch_bounds__(BS) void msg_kernel(
    const int* __restrict__ src, const float* __restrict__ eattr,
    const float* __restrict__ eW1, const float* __restrict__ eb1,
    const float* __restrict__ eW2, const float* __restrict__ eb2,
    const YT* __restrict__ Y, float* __restrict__ msg, int E)
{
    int e = blockIdx.x * BS + threadIdx.x;
    bool valid = e < E;
    int ee = valid ? e : 0;

    // edge trunk (fully unrolled, er stays in registers)
    float ea[16];
#pragma unroll
    for (int i = 0; i < 16; i += 4)
        *(float4*)(ea + i) = *(const float4*)(eattr + (size_t)ee * 16 + i);
    float h[32];
#pragma unroll
    for (int j = 0; j < 32; j++) {
        float s = eb1[j];
#pragma unroll
        for (int i = 0; i < 16; i++) s = fmaf(ea[i], eW1[i * 32 + j], s);
        h[j] = fmaxf(s, 0.f);
    }
    float er[16];
#pragma unroll
    for (int j = 0; j < 16; j++) {
        float s = eb2[j];
#pragma unroll
        for (int i = 0; i < 32; i++) s = fmaf(h[i], eW2[i * 16 + j], s);
        er[j] = 1.f / (1.f + __expf(-s));
    }

    const YT* y = Y + (size_t)src[ee] * 408;
    float acc[24];
#pragma unroll
    for (int j = 0; j < 24; j += 4) {
        float4 v = ldY4(y + 16 * 24 + j);
        acc[j] = v.x; acc[j + 1] = v.y; acc[j + 2] = v.z; acc[j + 3] = v.w;
    }
#pragma unroll
    for (int k = 0; k < 16; k++) {
        float ek = er[k];
#pragma unroll
        for (int j = 0; j < 24; j += 4) {
            float4 v = ldY4(y + k * 24 + j);
            acc[j]     = fmaf(ek, v.x, acc[j]);
            acc[j + 1] = fmaf(ek, v.y, acc[j + 1]);
            acc[j + 2] = fmaf(ek, v.z, acc[j + 2]);
            acc[j + 3] = fmaf(ek, v.w, acc[j + 3]);
        }
    }
    if (valid) {
        float* m = msg + (size_t)e * 24;
#pragma unroll
        for (int j = 0; j < 24; j += 4)
            *(float4*)(m + j) = make_float4(acc[j], acc[j + 1], acc[j + 2], acc[j + 3]);
    }
}

// ---- per-node gather + root transform + relu ----
template <int IN>
__global__ void gather_kernel(const float* __restrict__ x,
                              const float* __restrict__ msg,
                              const int* __restrict__ offs,
                              const int* __restrict__ degi,
                              const int* __restrict__ eid,
                              const float* __restrict__ rootW,
                              const float* __restrict__ bias,
                              float* __restrict__ out, int N)
{
    int n = blockIdx.x * blockDim.x + threadIdx.x;
    if (n >= N) return;

    float am[8], ax[8], aa[8];
#pragma unroll
    for (int o = 0; o < 8; o++) { am[o] = 0.f; aa[o] = 0.f; ax[o] = -3.402823466e38f; }

    int off = offs[n];
    int d = degi[n];
    for (int j = 0; j < d; j++) {
        int e = eid[off + j];
        const float* m = msg + (size_t)e * 24;
        float4 m0 = *(const float4*)(m + 0);
        float4 m1 = *(const float4*)(m + 4);
        float4 m2 = *(const float4*)(m + 8);
        float4 m3 = *(const float4*)(m + 12);
        float4 m4 = *(const float4*)(m + 16);
        float4 m5 = *(const float4*)(m + 20);
        am[0] += m0.x; am[1] += m0.y; am[2] += m0.z; am[3] += m0.w;
        am[4] += m1.x; am[5] += m1.y; am[6] += m1.z; am[7] += m1.w;
        ax[0] = fmaxf(ax[0], m2.x); ax[1] = fmaxf(ax[1], m2.y);
        ax[2] = fmaxf(ax[2], m2.z); ax[3] = fmaxf(ax[3], m2.w);
        ax[4] = fmaxf(ax[4], m3.x); ax[5] = fmaxf(ax[5], m3.y);
        ax[6] = fmaxf(ax[6], m3.z); ax[7] = fmaxf(ax[7], m3.w);
        aa[0] += m4.x; aa[1] += m4.y; aa[2] += m4.z; aa[3] += m4.w;
        aa[4] += m5.x; aa[5] += m5.y; aa[6] += m5.z; aa[7] += m5.w;
    }

    float xv[IN];
#pragma unroll
    for (int i = 0; i < IN; i += 4)
        *(float4*)(xv + i) = *(const float4*)(x + (size_t)n * IN + i);

    float inv = 1.f / fmaxf((float)d, 1.f);
    float r[24];
#pragma unroll
    for (int a = 0; a < 3; a++) {
#pragma unroll
        for (int o = 0; o < 8; o++) {
            float s = bias[a * 8 + o];
#pragma unroll
            for (int i = 0; i < IN; i++) s = fmaf(xv[i], rootW[(a * IN + i) * 8 + o], s);
            r[a * 8 + o] = s;
        }
    }
#pragma unroll
    for (int o = 0; o < 8; o++) {
        r[o]      += am[o] * inv;
        r[8 + o]  += (d > 0) ? ax[o] : 0.f;
        r[16 + o] += aa[o];
    }
#pragma unroll
    for (int j = 0; j < 24; j++)
        out[(size_t)n * 24 + j] = fmaxf(r[j], 0.f);
}

// ---- output head ----
__global__ void head_kernel(const float* __restrict__ x, const float* __restrict__ W,
                            const float* __restrict__ b, float* __restrict__ out, int N)
{
    int n = blockIdx.x * blockDim.x + threadIdx.x;
    if (n >= N) return;
    float l0 = b[0], l1 = b[1];
#pragma unroll
    for (int i = 0; i < 24; i++) {
        float xi = x[(size_t)n * 24 + i];
        l0 = fmaf(xi, W[i * 2 + 0], l0);
        l1 = fmaf(xi, W[i * 2 + 1], l1);
    }
    out[2 * (size_t)n + 0] = l0;
    out[2 * (size_t)n + 1] = l1;
    float m = fmaxf(l0, l1);
    float e0 = __expf(l0 - m), e1 = __expf(l1 - m);
    float s = e0 + e1;
    out[2 * (size_t)N + 2 * (size_t)n + 0] = e0 / s;
    out[2 * (size_t)N + 2 * (size_t)n + 1] = e1 / s;
}

// ---------------- launcher (templated on Y storage type) ----------------
template <typename YT>
static void run_all(void* const* d_in, int N, int E, void* d_ws, hipStream_t stream,
                    void* d_out)
{
    const float* x_feat = (const float*)d_in[0];
    const int*   eidx   = (const int*)d_in[1];
    const float* eattr  = (const float*)d_in[2];
    const float* lpW = (const float*)d_in[3];
    const float* lpb = (const float*)d_in[4];
    const float* tW  = (const float*)d_in[5];
    const float* tb  = (const float*)d_in[6];
    const float* eW1 = (const float*)d_in[7];
    const float* eb1 = (const float*)d_in[8];
    const float* eW2 = (const float*)d_in[9];
    const float* eb2 = (const float*)d_in[10];
    const float* c1W = (const float*)d_in[11];
    const float* c1B = (const float*)d_in[12];
    const float* c1R = (const float*)d_in[13];
    const float* c1b = (const float*)d_in[14];
    const float* c2W = (const float*)d_in[15];
    const float* c2B = (const float*)d_in[16];
    const float* c2R = (const float*)d_in[17];
    const float* c2b = (const float*)d_in[18];
    const float* oW  = (const float*)d_in[19];
    const float* ob  = (const float*)d_in[20];

    const int* src = eidx;
    const int* dstI = eidx + E;

    char* wsb = (char*)d_ws;
    size_t off = 0;
    auto alloc = [&](size_t bytes) {
        off = (off + 255) & ~(size_t)255;
        void* p = wsb + off;
        off += bytes;
        return p;
    };
    YT* Y       = (YT*)alloc((size_t)N * 408 * sizeof(YT));
    float* msg  = (float*)alloc((size_t)E * 24 * sizeof(float));
    float* x16  = (float*)alloc((size_t)N * 16 * sizeof(float));
    float* x24a = (float*)alloc((size_t)N * 24 * sizeof(float));
    float* x24b = (float*)alloc((size_t)N * 24 * sizeof(float));
    int* degi   = (int*)alloc(((size_t)N + 1) * sizeof(int));  // +1: cursor
    int* cursor = degi + N;
    int* offs   = (int*)alloc((size_t)N * sizeof(int));
    int* cur    = (int*)alloc((size_t)N * sizeof(int));
    int* eid    = (int*)alloc((size_t)E * sizeof(int));

    dim3 blk(BS);
    int nb_nodes = (N + BS - 1) / BS;
    int nb_edges = (E + BS - 1) / BS;

    hipMemsetAsync(degi, 0, (N + 1) * sizeof(int), stream);

    prep_kernel<<<nb_nodes, blk, 0, stream>>>(x_feat, lpW, lpb, tW, tb, x16, N);
    deg_kernel<<<nb_edges, blk, 0, stream>>>(dstI, degi, E);
    offsets_kernel<<<nb_nodes, blk, 0, stream>>>(degi, offs, cur, cursor, N);
    fill_kernel<<<nb_edges, blk, 0, stream>>>(dstI, cur, eid, E);

    // ---- conv1 ----
    ynode_kernel<16, YT><<<nb_nodes, blk, 0, stream>>>(x16, c1W, c1B, Y, N);
    msg_kernel<YT><<<nb_edges, blk, 0, stream>>>(src, eattr, eW1, eb1, eW2, eb2, Y, msg, E);
    gather_kernel<16><<<nb_nodes, blk, 0, stream>>>(x16, msg, offs, degi, eid, c1R, c1b, x24a, N);

    // ---- conv2 ----
    ynode_kernel<24, YT><<<nb_nodes, blk, 0, stream>>>(x24a, c2W, c2B, Y, N);
    msg_kernel<YT><<<nb_edges, blk, 0, stream>>>(src, eattr, eW1, eb1, eW2, eb2, Y, msg, E);
    gather_kernel<24><<<nb_nodes, blk, 0, stream>>>(x24a, msg, offs, degi, eid, c2R, c2b, x24b, N);

    head_kernel<<<nb_nodes, blk, 0, stream>>>(x24b, oW, ob, (float*)d_out, N);
}

extern "C" void kernel_launch(void* const* d_in, const int* in_sizes, int n_in,
                              void* d_out, int out_size, void* d_ws, size_t ws_size,
                              hipStream_t stream)
{
    int N = in_sizes[0] / 24;
    int E = in_sizes[1] / 2;

    // fp32-Y needs ~145 MB of ws; fall back to bf16 Y if ws is smaller
    size_t needF32 = (size_t)N * 408 * 4 + (size_t)E * 24 * 4 + (size_t)N * 16 * 4 +
                     (size_t)N * 24 * 4 * 2 + (size_t)(N * 3 + 1 + E) * 4 + 4096;
    if (ws_size >= needF32)
        run_all<float>(d_in, N, E, d_ws, stream, d_out);
    else
        run_all<unsigned short>(d_in, N, E, d_ws, stream, d_out);
}

// Round 4
// 587.992 us; speedup vs baseline: 2.3711x; 2.3711x over previous
//
#include <hip/hip_runtime.h>

#define BS 256

// ---------------- bf16 helpers ----------------
__device__ __forceinline__ unsigned short f2bf(float f) {
    unsigned x = __float_as_uint(f);
    return (unsigned short)((x + 0x7fffu + ((x >> 16) & 1u)) >> 16);
}
__device__ __forceinline__ void unpack8(uint4 v, float* d) {
    d[0] = __uint_as_float(v.x << 16); d[1] = __uint_as_float(v.x & 0xFFFF0000u);
    d[2] = __uint_as_float(v.y << 16); d[3] = __uint_as_float(v.y & 0xFFFF0000u);
    d[4] = __uint_as_float(v.z << 16); d[5] = __uint_as_float(v.z & 0xFFFF0000u);
    d[6] = __uint_as_float(v.w << 16); d[7] = __uint_as_float(v.w & 0xFFFF0000u);
}
// store 24 floats as 24 bf16 (48 B = 3x uint4)
__device__ __forceinline__ void st24bf(unsigned short* p, const float* r) {
    unsigned w[12];
#pragma unroll
    for (int j = 0; j < 12; j++)
        w[j] = (unsigned)f2bf(r[2 * j]) | ((unsigned)f2bf(r[2 * j + 1]) << 16);
    uint4* q = (uint4*)p;
    q[0] = make_uint4(w[0], w[1], w[2], w[3]);
    q[1] = make_uint4(w[4], w[5], w[6], w[7]);
    q[2] = make_uint4(w[8], w[9], w[10], w[11]);
}

// ---- node prep: x16 = relu(relu(x_feat @ lpW + lpb) @ tW + tb) ----
__global__ void prep_kernel(const float* __restrict__ xf,
                            const float* __restrict__ W1, const float* __restrict__ b1,
                            const float* __restrict__ W2, const float* __restrict__ b2,
                            float* __restrict__ x16, int N)
{
    int n = blockIdx.x * blockDim.x + threadIdx.x;
    bool valid = n < N;
    int nn = valid ? n : 0;
    float a[24];
#pragma unroll
    for (int i = 0; i < 24; i += 4)
        *(float4*)(a + i) = *(const float4*)(xf + (size_t)nn * 24 + i);
    float h[32];
#pragma unroll
    for (int j = 0; j < 32; j++) {
        float s = b1[j];
#pragma unroll
        for (int i = 0; i < 24; i++) s = fmaf(a[i], W1[i * 32 + j], s);
        h[j] = fmaxf(s, 0.f);
    }
    if (!valid) return;
#pragma unroll
    for (int j = 0; j < 16; j++) {
        float s = b2[j];
#pragma unroll
        for (int i = 0; i < 32; i++) s = fmaf(h[i], W2[i * 16 + j], s);
        x16[(size_t)n * 16 + j] = fmaxf(s, 0.f);
    }
}

// ---- CSR build (generic over index array) ----
__global__ void deg_kernel(const int* __restrict__ idx, int* __restrict__ cnt, int E)
{
    int i = blockIdx.x * blockDim.x + threadIdx.x;
    if (i < E) atomicAdd(&cnt[idx[i]], 1);
}
__global__ void offsets_kernel(const int* __restrict__ cnt, int* __restrict__ offs,
                               int* __restrict__ cur, int* __restrict__ cursor, int N)
{
    int n = blockIdx.x * blockDim.x + threadIdx.x;
    if (n < N) {
        int d = cnt[n];
        int o = atomicAdd(cursor, d);
        offs[n] = o;
        cur[n] = o;
    }
}
// src fill: sorted position p for each edge; record e->p (rank) and src node per p
__global__ void fill_src_kernel(const int* __restrict__ srcA, int* __restrict__ cur,
                                int* __restrict__ eid_src, int* __restrict__ rank,
                                int* __restrict__ srcnode, int E)
{
    int e = blockIdx.x * blockDim.x + threadIdx.x;
    if (e < E) {
        int s = srcA[e];
        int p = atomicAdd(&cur[s], 1);
        eid_src[p] = e;
        rank[e] = p;
        srcnode[p] = s;
    }
}
// dst fill: store msg-row id (= rank[e]) directly so gather needs no extra hop
__global__ void fill_dst_kernel(const int* __restrict__ dstA, int* __restrict__ cur,
                                const int* __restrict__ rank, int* __restrict__ eidm, int E)
{
    int e = blockIdx.x * blockDim.x + threadIdx.x;
    if (e < E) {
        int q = atomicAdd(&cur[dstA[e]], 1);
        eidm[q] = rank[e];
    }
}

// ---- per-node Y precompute: Y[n, k, a*8+o] = sum_i x[i]*W[a,k,i*8+o]; slot16 = x@B ----
template <int IN>
__global__ __launch_bounds__(BS) void ynode_kernel(const float* __restrict__ x,
                                                   const float* __restrict__ W,  // [3][16][IN*8]
                                                   const float* __restrict__ B,  // [3][IN*8]
                                                   unsigned short* __restrict__ Y, int N)
{
    int n = blockIdx.x * BS + threadIdx.x;
    bool valid = n < N;
    int nn = valid ? n : 0;
    float xv[IN];
#pragma unroll
    for (int i = 0; i < IN; i += 4)
        *(float4*)(xv + i) = *(const float4*)(x + (size_t)nn * IN + i);
    unsigned short* yr = Y + (size_t)nn * 408;

    for (int k = 0; k < 16; k++) {   // rolled: weights s_loaded per iter (uniform)
        float r[24];
#pragma unroll
        for (int j = 0; j < 24; j++) r[j] = 0.f;
        const float* w = W + (size_t)k * (IN * 8);
#pragma unroll
        for (int a = 0; a < 3; a++) {
            const float* wa = w + (size_t)a * (16 * IN * 8);
#pragma unroll
            for (int i = 0; i < IN; i++) {
                float xi = xv[i];
#pragma unroll
                for (int o = 0; o < 8; o++)
                    r[a * 8 + o] = fmaf(xi, wa[i * 8 + o], r[a * 8 + o]);
            }
        }
        if (valid) st24bf(yr + k * 24, r);
    }
    {   // bias slot (k=16): sum_i x[i]*B[a, i*8+o]
        float r[24];
#pragma unroll
        for (int j = 0; j < 24; j++) r[j] = 0.f;
#pragma unroll
        for (int a = 0; a < 3; a++) {
            const float* ba = B + (size_t)a * (IN * 8);
#pragma unroll
            for (int i = 0; i < IN; i++) {
                float xi = xv[i];
#pragma unroll
                for (int o = 0; o < 8; o++)
                    r[a * 8 + o] = fmaf(xi, ba[i * 8 + o], r[a * 8 + o]);
            }
        }
        if (valid) st24bf(yr + 16 * 24, r);
    }
}

// ---- per-sorted-edge msg: msg[p,:] = sum_k er[k]*Y[srcnode[p],k,:] + Y[.,16,:] ----
// COMPUTE_ER: run edge trunk (random eattr read) and store er_s; else load er_s.
template <bool COMPUTE_ER>
__global__ __launch_bounds__(BS) void msg_kernel(
    const int* __restrict__ srcnode, const int* __restrict__ eid_src,
    const float* __restrict__ eattr,
    const float* __restrict__ eW1, const float* __restrict__ eb1,
    const float* __restrict__ eW2, const float* __restrict__ eb2,
    unsigned short* __restrict__ er_s,   // [E][16] bf16, sorted order
    const unsigned short* __restrict__ Y,
    float* __restrict__ msg, int E)
{
    int p = blockIdx.x * BS + threadIdx.x;
    if (p >= E) return;

    float er[16];
    if (COMPUTE_ER) {
        int e = eid_src[p];
        float ea[16];
#pragma unroll
        for (int i = 0; i < 16; i += 4)
            *(float4*)(ea + i) = *(const float4*)(eattr + (size_t)e * 16 + i);
        float h[32];
#pragma unroll
        for (int j = 0; j < 32; j++) {
            float s = eb1[j];
#pragma unroll
            for (int i = 0; i < 16; i++) s = fmaf(ea[i], eW1[i * 32 + j], s);
            h[j] = fmaxf(s, 0.f);
        }
#pragma unroll
        for (int j = 0; j < 16; j++) {
            float s = eb2[j];
#pragma unroll
            for (int i = 0; i < 32; i++) s = fmaf(h[i], eW2[i * 16 + j], s);
            er[j] = 1.f / (1.f + __expf(-s));
        }
        unsigned w[8];
#pragma unroll
        for (int j = 0; j < 8; j++)
            w[j] = (unsigned)f2bf(er[2 * j]) | ((unsigned)f2bf(er[2 * j + 1]) << 16);
        uint4* q = (uint4*)(er_s + (size_t)p * 16);
        q[0] = make_uint4(w[0], w[1], w[2], w[3]);
        q[1] = make_uint4(w[4], w[5], w[6], w[7]);
    } else {
        const uint4* eu = (const uint4*)(er_s + (size_t)p * 16);
        uint4 e0 = eu[0], e1 = eu[1];
        unpack8(e0, er);
        unpack8(e1, er + 8);
    }

    int s = srcnode[p];
    const uint4* yu = (const uint4*)(Y + (size_t)s * 408);

    float acc[24];
    {   // bias slot (k=16): uint4 indices 48..50
        float t[8];
        unpack8(yu[48], t);
#pragma unroll
        for (int j = 0; j < 8; j++) acc[j] = t[j];
        unpack8(yu[49], t);
#pragma unroll
        for (int j = 0; j < 8; j++) acc[8 + j] = t[j];
        unpack8(yu[50], t);
#pragma unroll
        for (int j = 0; j < 8; j++) acc[16 + j] = t[j];
    }
#pragma unroll
    for (int k = 0; k < 16; k++) {
        float ek = er[k];
        float t[8];
        unpack8(yu[k * 3 + 0], t);
#pragma unroll
        for (int j = 0; j < 8; j++) acc[j] = fmaf(ek, t[j], acc[j]);
        unpack8(yu[k * 3 + 1], t);
#pragma unroll
        for (int j = 0; j < 8; j++) acc[8 + j] = fmaf(ek, t[j], acc[8 + j]);
        unpack8(yu[k * 3 + 2], t);
#pragma unroll
        for (int j = 0; j < 8; j++) acc[16 + j] = fmaf(ek, t[j], acc[16 + j]);
    }

    float* m = msg + (size_t)p * 24;
#pragma unroll
    for (int j = 0; j < 24; j += 4)
        *(float4*)(m + j) = make_float4(acc[j], acc[j + 1], acc[j + 2], acc[j + 3]);
}

// ---- per-node gather + root transform + relu (eidm holds msg-row ids) ----
template <int IN>
__global__ void gather_kernel(const float* __restrict__ x,
                              const float* __restrict__ msg,
                              const int* __restrict__ offs,
                              const int* __restrict__ degi,
                              const int* __restrict__ eidm,
                              const float* __restrict__ rootW,
                              const float* __restrict__ bias,
                              float* __restrict__ out, int N)
{
    int n = blockIdx.x * blockDim.x + threadIdx.x;
    if (n >= N) return;

    float am[8], ax[8], aa[8];
#pragma unroll
    for (int o = 0; o < 8; o++) { am[o] = 0.f; aa[o] = 0.f; ax[o] = -3.402823466e38f; }

    int off = offs[n];
    int d = degi[n];
    for (int j = 0; j < d; j++) {
        int r = eidm[off + j];
        const float* m = msg + (size_t)r * 24;
        float4 m0 = *(const float4*)(m + 0);
        float4 m1 = *(const float4*)(m + 4);
        float4 m2 = *(const float4*)(m + 8);
        float4 m3 = *(const float4*)(m + 12);
        float4 m4 = *(const float4*)(m + 16);
        float4 m5 = *(const float4*)(m + 20);
        am[0] += m0.x; am[1] += m0.y; am[2] += m0.z; am[3] += m0.w;
        am[4] += m1.x; am[5] += m1.y; am[6] += m1.z; am[7] += m1.w;
        ax[0] = fmaxf(ax[0], m2.x); ax[1] = fmaxf(ax[1], m2.y);
        ax[2] = fmaxf(ax[2], m2.z); ax[3] = fmaxf(ax[3], m2.w);
        ax[4] = fmaxf(ax[4], m3.x); ax[5] = fmaxf(ax[5], m3.y);
        ax[6] = fmaxf(ax[6], m3.z); ax[7] = fmaxf(ax[7], m3.w);
        aa[0] += m4.x; aa[1] += m4.y; aa[2] += m4.z; aa[3] += m4.w;
        aa[4] += m5.x; aa[5] += m5.y; aa[6] += m5.z; aa[7] += m5.w;
    }

    float xv[IN];
#pragma unroll
    for (int i = 0; i < IN; i += 4)
        *(float4*)(xv + i) = *(const float4*)(x + (size_t)n * IN + i);

    float inv = 1.f / fmaxf((float)d, 1.f);
    float r[24];
#pragma unroll
    for (int a = 0; a < 3; a++) {
#pragma unroll
        for (int o = 0; o < 8; o++) {
            float s = bias[a * 8 + o];
#pragma unroll
            for (int i = 0; i < IN; i++) s = fmaf(xv[i], rootW[(a * IN + i) * 8 + o], s);
            r[a * 8 + o] = s;
        }
    }
#pragma unroll
    for (int o = 0; o < 8; o++) {
        r[o]      += am[o] * inv;
        r[8 + o]  += (d > 0) ? ax[o] : 0.f;
        r[16 + o] += aa[o];
    }
#pragma unroll
    for (int j = 0; j < 24; j++)
        out[(size_t)n * 24 + j] = fmaxf(r[j], 0.f);
}

// ---- output head ----
__global__ void head_kernel(const float* __restrict__ x, const float* __restrict__ W,
                            const float* __restrict__ b, float* __restrict__ out, int N)
{
    int n = blockIdx.x * blockDim.x + threadIdx.x;
    if (n >= N) return;
    float l0 = b[0], l1 = b[1];
#pragma unroll
    for (int i = 0; i < 24; i++) {
        float xi = x[(size_t)n * 24 + i];
        l0 = fmaf(xi, W[i * 2 + 0], l0);
        l1 = fmaf(xi, W[i * 2 + 1], l1);
    }
    out[2 * (size_t)n + 0] = l0;
    out[2 * (size_t)n + 1] = l1;
    float m = fmaxf(l0, l1);
    float e0 = __expf(l0 - m), e1 = __expf(l1 - m);
    float s = e0 + e1;
    out[2 * (size_t)N + 2 * (size_t)n + 0] = e0 / s;
    out[2 * (size_t)N + 2 * (size_t)n + 1] = e1 / s;
}

extern "C" void kernel_launch(void* const* d_in, const int* in_sizes, int n_in,
                              void* d_out, int out_size, void* d_ws, size_t ws_size,
                              hipStream_t stream)
{
    const float* x_feat = (const float*)d_in[0];
    const int*   eidx   = (const int*)d_in[1];
    const float* eattr  = (const float*)d_in[2];
    const float* lpW = (const float*)d_in[3];
    const float* lpb = (const float*)d_in[4];
    const float* tW  = (const float*)d_in[5];
    const float* tb  = (const float*)d_in[6];
    const float* eW1 = (const float*)d_in[7];
    const float* eb1 = (const float*)d_in[8];
    const float* eW2 = (const float*)d_in[9];
    const float* eb2 = (const float*)d_in[10];
    const float* c1W = (const float*)d_in[11];
    const float* c1B = (const float*)d_in[12];
    const float* c1R = (const float*)d_in[13];
    const float* c1b = (const float*)d_in[14];
    const float* c2W = (const float*)d_in[15];
    const float* c2B = (const float*)d_in[16];
    const float* c2R = (const float*)d_in[17];
    const float* c2b = (const float*)d_in[18];
    const float* oW  = (const float*)d_in[19];
    const float* ob  = (const float*)d_in[20];

    int N = in_sizes[0] / 24;
    int E = in_sizes[1] / 2;
    const int* srcA = eidx;
    const int* dstA = eidx + E;

    char* wsb = (char*)d_ws;
    size_t off = 0;
    auto alloc = [&](size_t bytes) {
        off = (off + 255) & ~(size_t)255;
        void* p = wsb + off;
        off += bytes;
        return p;
    };
    unsigned short* Y    = (unsigned short*)alloc((size_t)N * 408 * 2);
    float* msg  = (float*)alloc((size_t)E * 24 * 4);
    unsigned short* er_s = (unsigned short*)alloc((size_t)E * 16 * 2);
    float* x16  = (float*)alloc((size_t)N * 16 * 4);
    float* x24a = (float*)alloc((size_t)N * 24 * 4);
    float* x24b = (float*)alloc((size_t)N * 24 * 4);
    int* ibase  = (int*)alloc(((size_t)2 * N + 2) * 4);  // degD | cntS | cursD | cursS (zeroed)
    int* degD = ibase;
    int* cntS = ibase + N;
    int* cursD = ibase + 2 * N;
    int* cursS = ibase + 2 * N + 1;
    int* offsD = (int*)alloc((size_t)N * 4);
    int* curD  = (int*)alloc((size_t)N * 4);
    int* offsS = (int*)alloc((size_t)N * 4);
    int* curS  = (int*)alloc((size_t)N * 4);
    int* eid_src = (int*)alloc((size_t)E * 4);
    int* rank    = (int*)alloc((size_t)E * 4);
    int* srcnode = (int*)alloc((size_t)E * 4);
    int* eidm    = (int*)alloc((size_t)E * 4);

    dim3 blk(BS);
    int nb_nodes = (N + BS - 1) / BS;
    int nb_edges = (E + BS - 1) / BS;

    hipMemsetAsync(ibase, 0, (2 * (size_t)N + 2) * 4, stream);

    prep_kernel<<<nb_nodes, blk, 0, stream>>>(x_feat, lpW, lpb, tW, tb, x16, N);

    // CSR by dst (for gather) and by src (for msg locality)
    deg_kernel<<<nb_edges, blk, 0, stream>>>(dstA, degD, E);
    deg_kernel<<<nb_edges, blk, 0, stream>>>(srcA, cntS, E);
    offsets_kernel<<<nb_nodes, blk, 0, stream>>>(degD, offsD, curD, cursD, N);
    offsets_kernel<<<nb_nodes, blk, 0, stream>>>(cntS, offsS, curS, cursS, N);
    fill_src_kernel<<<nb_edges, blk, 0, stream>>>(srcA, curS, eid_src, rank, srcnode, E);
    fill_dst_kernel<<<nb_edges, blk, 0, stream>>>(dstA, curD, rank, eidm, E);

    // ---- conv1 (computes er_s) ----
    ynode_kernel<16><<<nb_nodes, blk, 0, stream>>>(x16, c1W, c1B, Y, N);
    msg_kernel<true><<<nb_edges, blk, 0, stream>>>(srcnode, eid_src, eattr,
                                                   eW1, eb1, eW2, eb2, er_s, Y, msg, E);
    gather_kernel<16><<<nb_nodes, blk, 0, stream>>>(x16, msg, offsD, degD, eidm, c1R, c1b, x24a, N);

    // ---- conv2 (reuses er_s) ----
    ynode_kernel<24><<<nb_nodes, blk, 0, stream>>>(x24a, c2W, c2B, Y, N);
    msg_kernel<false><<<nb_edges, blk, 0, stream>>>(srcnode, eid_src, eattr,
                                                    eW1, eb1, eW2, eb2, er_s, Y, msg, E);
    gather_kernel<24><<<nb_nodes, blk, 0, stream>>>(x24a, msg, offsD, degD, eidm, c2R, c2b, x24b, N);

    head_kernel<<<nb_nodes, blk, 0, stream>>>(x24b, oW, ob, (float*)d_out, N);
}

// Round 5
// 467.593 us; speedup vs baseline: 2.9816x; 1.2575x over previous
//
#include <hip/hip_runtime.h>

#define BS 256

// ---------------- bf16 helpers ----------------
__device__ __forceinline__ unsigned short f2bf(float f) {
    unsigned x = __float_as_uint(f);
    return (unsigned short)((x + 0x7fffu + ((x >> 16) & 1u)) >> 16);
}
__device__ __forceinline__ void unpack8(uint4 v, float* d) {
    d[0] = __uint_as_float(v.x << 16); d[1] = __uint_as_float(v.x & 0xFFFF0000u);
    d[2] = __uint_as_float(v.y << 16); d[3] = __uint_as_float(v.y & 0xFFFF0000u);
    d[4] = __uint_as_float(v.z << 16); d[5] = __uint_as_float(v.z & 0xFFFF0000u);
    d[6] = __uint_as_float(v.w << 16); d[7] = __uint_as_float(v.w & 0xFFFF0000u);
}
// store 24 floats as 24 bf16 (48 B = 3x uint4)
__device__ __forceinline__ void st24bf(unsigned short* p, const float* r) {
    unsigned w[12];
#pragma unroll
    for (int j = 0; j < 12; j++)
        w[j] = (unsigned)f2bf(r[2 * j]) | ((unsigned)f2bf(r[2 * j + 1]) << 16);
    uint4* q = (uint4*)p;
    q[0] = make_uint4(w[0], w[1], w[2], w[3]);
    q[1] = make_uint4(w[4], w[5], w[6], w[7]);
    q[2] = make_uint4(w[8], w[9], w[10], w[11]);
}

// ---- node prep: x16 = relu(relu(x_feat @ lpW + lpb) @ tW + tb) ----
__global__ void prep_kernel(const float* __restrict__ xf,
                            const float* __restrict__ W1, const float* __restrict__ b1,
                            const float* __restrict__ W2, const float* __restrict__ b2,
                            float* __restrict__ x16, int N)
{
    int n = blockIdx.x * blockDim.x + threadIdx.x;
    bool valid = n < N;
    int nn = valid ? n : 0;
    float a[24];
#pragma unroll
    for (int i = 0; i < 24; i += 4)
        *(float4*)(a + i) = *(const float4*)(xf + (size_t)nn * 24 + i);
    float h[32];
#pragma unroll
    for (int j = 0; j < 32; j++) {
        float s = b1[j];
#pragma unroll
        for (int i = 0; i < 24; i++) s = fmaf(a[i], W1[i * 32 + j], s);
        h[j] = fmaxf(s, 0.f);
    }
    if (!valid) return;
#pragma unroll
    for (int j = 0; j < 16; j++) {
        float s = b2[j];
#pragma unroll
        for (int i = 0; i < 32; i++) s = fmaf(h[i], W2[i * 16 + j], s);
        x16[(size_t)n * 16 + j] = fmaxf(s, 0.f);
    }
}

// ---- CSR build (fused: both src and dst sides) ----
__global__ void deg2_kernel(const int* __restrict__ srcA, const int* __restrict__ dstA,
                            int* __restrict__ cntS, int* __restrict__ degD, int E)
{
    int i = blockIdx.x * blockDim.x + threadIdx.x;
    if (i < E) {
        atomicAdd(&cntS[srcA[i]], 1);
        atomicAdd(&degD[dstA[i]], 1);
    }
}
__global__ void offsets2_kernel(const int* __restrict__ cntS, const int* __restrict__ degD,
                                int* __restrict__ offsS, int* __restrict__ curS,
                                int* __restrict__ offsD, int* __restrict__ curD,
                                int* __restrict__ cursS, int* __restrict__ cursD, int N)
{
    int n = blockIdx.x * blockDim.x + threadIdx.x;
    if (n < N) {
        int dS = cntS[n];
        int oS = atomicAdd(cursS, dS);
        offsS[n] = oS; curS[n] = oS;
        int dD = degD[n];
        int oD = atomicAdd(cursD, dD);
        offsD[n] = oD; curD[n] = oD;
    }
}
// fused fill: sorted src position p (msg row); dst list stores p directly
__global__ void fill2_kernel(const int* __restrict__ srcA, const int* __restrict__ dstA,
                             int* __restrict__ curS, int* __restrict__ curD,
                             int* __restrict__ eid_src, int* __restrict__ srcnode,
                             int* __restrict__ eidm, int E)
{
    int e = blockIdx.x * blockDim.x + threadIdx.x;
    if (e < E) {
        int s = srcA[e];
        int p = atomicAdd(&curS[s], 1);
        eid_src[p] = e;
        srcnode[p] = s;
        int q = atomicAdd(&curD[dstA[e]], 1);
        eidm[q] = p;
    }
}

// ---- per-(node, k-slot) Y precompute: grid.y = 17 slots; slot16 = x@B ----
template <int IN>
__global__ __launch_bounds__(BS) void ynode_kernel(const float* __restrict__ x,
                                                   const float* __restrict__ W,  // [3][16][IN*8]
                                                   const float* __restrict__ B,  // [3][IN*8]
                                                   unsigned short* __restrict__ Y, int N)
{
    int n = blockIdx.x * BS + threadIdx.x;
    int k = blockIdx.y;            // 0..16, block-uniform
    bool valid = n < N;
    int nn = valid ? n : 0;
    float xv[IN];
#pragma unroll
    for (int i = 0; i < IN; i += 4)
        *(float4*)(xv + i) = *(const float4*)(x + (size_t)nn * IN + i);

    float r[24];
#pragma unroll
    for (int j = 0; j < 24; j++) r[j] = 0.f;

    if (k < 16) {
        const float* w = W + (size_t)k * (IN * 8);
#pragma unroll
        for (int a = 0; a < 3; a++) {
            const float* wa = w + (size_t)a * (16 * IN * 8);
#pragma unroll
            for (int i = 0; i < IN; i++) {
                float xi = xv[i];
#pragma unroll
                for (int o = 0; o < 8; o++)
                    r[a * 8 + o] = fmaf(xi, wa[i * 8 + o], r[a * 8 + o]);
            }
        }
    } else {
#pragma unroll
        for (int a = 0; a < 3; a++) {
            const float* ba = B + (size_t)a * (IN * 8);
#pragma unroll
            for (int i = 0; i < IN; i++) {
                float xi = xv[i];
#pragma unroll
                for (int o = 0; o < 8; o++)
                    r[a * 8 + o] = fmaf(xi, ba[i * 8 + o], r[a * 8 + o]);
            }
        }
    }
    if (valid) st24bf(Y + (size_t)n * 408 + k * 24, r);
}

// ---- per-sorted-edge msg: msg[p,:] = sum_k er[k]*Y[srcnode[p],k,:] + Y[.,16,:] ----
template <bool COMPUTE_ER>
__global__ __launch_bounds__(BS) void msg_kernel(
    const int* __restrict__ srcnode, const int* __restrict__ eid_src,
    const float* __restrict__ eattr,
    const float* __restrict__ eW1, const float* __restrict__ eb1,
    const float* __restrict__ eW2, const float* __restrict__ eb2,
    unsigned short* __restrict__ er_s,   // [E][16] bf16, sorted order
    const unsigned short* __restrict__ Y,
    float* __restrict__ msg, int E)
{
    int p = blockIdx.x * BS + threadIdx.x;
    if (p >= E) return;

    float er[16];
    if (COMPUTE_ER) {
        int e = eid_src[p];
        float ea[16];
#pragma unroll
        for (int i = 0; i < 16; i += 4)
            *(float4*)(ea + i) = *(const float4*)(eattr + (size_t)e * 16 + i);
        float h[32];
#pragma unroll
        for (int j = 0; j < 32; j++) {
            float s = eb1[j];
#pragma unroll
            for (int i = 0; i < 16; i++) s = fmaf(ea[i], eW1[i * 32 + j], s);
            h[j] = fmaxf(s, 0.f);
        }
#pragma unroll
        for (int j = 0; j < 16; j++) {
            float s = eb2[j];
#pragma unroll
            for (int i = 0; i < 32; i++) s = fmaf(h[i], eW2[i * 16 + j], s);
            er[j] = 1.f / (1.f + __expf(-s));
        }
        unsigned w[8];
#pragma unroll
        for (int j = 0; j < 8; j++)
            w[j] = (unsigned)f2bf(er[2 * j]) | ((unsigned)f2bf(er[2 * j + 1]) << 16);
        uint4* q = (uint4*)(er_s + (size_t)p * 16);
        q[0] = make_uint4(w[0], w[1], w[2], w[3]);
        q[1] = make_uint4(w[4], w[5], w[6], w[7]);
    } else {
        const uint4* eu = (const uint4*)(er_s + (size_t)p * 16);
        uint4 e0 = eu[0], e1 = eu[1];
        unpack8(e0, er);
        unpack8(e1, er + 8);
    }

    int s = srcnode[p];
    const uint4* yu = (const uint4*)(Y + (size_t)s * 408);

    float acc[24];
    {   // bias slot (k=16): uint4 indices 48..50
        float t[8];
        unpack8(yu[48], t);
#pragma unroll
        for (int j = 0; j < 8; j++) acc[j] = t[j];
        unpack8(yu[49], t);
#pragma unroll
        for (int j = 0; j < 8; j++) acc[8 + j] = t[j];
        unpack8(yu[50], t);
#pragma unroll
        for (int j = 0; j < 8; j++) acc[16 + j] = t[j];
    }
#pragma unroll
    for (int k = 0; k < 16; k++) {
        float ek = er[k];
        float t[8];
        unpack8(yu[k * 3 + 0], t);
#pragma unroll
        for (int j = 0; j < 8; j++) acc[j] = fmaf(ek, t[j], acc[j]);
        unpack8(yu[k * 3 + 1], t);
#pragma unroll
        for (int j = 0; j < 8; j++) acc[8 + j] = fmaf(ek, t[j], acc[8 + j]);
        unpack8(yu[k * 3 + 2], t);
#pragma unroll
        for (int j = 0; j < 8; j++) acc[16 + j] = fmaf(ek, t[j], acc[16 + j]);
    }

    float* m = msg + (size_t)p * 24;
#pragma unroll
    for (int j = 0; j < 24; j += 4)
        *(float4*)(m + j) = make_float4(acc[j], acc[j + 1], acc[j + 2], acc[j + 3]);
}

// ---- per-node gather + root transform + relu (eidm holds msg-row ids) ----
template <int IN>
__global__ void gather_kernel(const float* __restrict__ x,
                              const float* __restrict__ msg,
                              const int* __restrict__ offs,
                              const int* __restrict__ degi,
                              const int* __restrict__ eidm,
                              const float* __restrict__ rootW,
                              const float* __restrict__ bias,
                              float* __restrict__ out, int N)
{
    int n = blockIdx.x * blockDim.x + threadIdx.x;
    if (n >= N) return;

    float am[8], ax[8], aa[8];
#pragma unroll
    for (int o = 0; o < 8; o++) { am[o] = 0.f; aa[o] = 0.f; ax[o] = -3.402823466e38f; }

    int off = offs[n];
    int d = degi[n];
    for (int j = 0; j < d; j++) {
        int r = eidm[off + j];
        const float* m = msg + (size_t)r * 24;
        float4 m0 = *(const float4*)(m + 0);
        float4 m1 = *(const float4*)(m + 4);
        float4 m2 = *(const float4*)(m + 8);
        float4 m3 = *(const float4*)(m + 12);
        float4 m4 = *(const float4*)(m + 16);
        float4 m5 = *(const float4*)(m + 20);
        am[0] += m0.x; am[1] += m0.y; am[2] += m0.z; am[3] += m0.w;
        am[4] += m1.x; am[5] += m1.y; am[6] += m1.z; am[7] += m1.w;
        ax[0] = fmaxf(ax[0], m2.x); ax[1] = fmaxf(ax[1], m2.y);
        ax[2] = fmaxf(ax[2], m2.z); ax[3] = fmaxf(ax[3], m2.w);
        ax[4] = fmaxf(ax[4], m3.x); ax[5] = fmaxf(ax[5], m3.y);
        ax[6] = fmaxf(ax[6], m3.z); ax[7] = fmaxf(ax[7], m3.w);
        aa[0] += m4.x; aa[1] += m4.y; aa[2] += m4.z; aa[3] += m4.w;
        aa[4] += m5.x; aa[5] += m5.y; aa[6] += m5.z; aa[7] += m5.w;
    }

    float xv[IN];
#pragma unroll
    for (int i = 0; i < IN; i += 4)
        *(float4*)(xv + i) = *(const float4*)(x + (size_t)n * IN + i);

    float inv = 1.f / fmaxf((float)d, 1.f);
    float r[24];
#pragma unroll
    for (int a = 0; a < 3; a++) {
#pragma unroll
        for (int o = 0; o < 8; o++) {
            float s = bias[a * 8 + o];
#pragma unroll
            for (int i = 0; i < IN; i++) s = fmaf(xv[i], rootW[(a * IN + i) * 8 + o], s);
            r[a * 8 + o] = s;
        }
    }
#pragma unroll
    for (int o = 0; o < 8; o++) {
        r[o]      += am[o] * inv;
        r[8 + o]  += (d > 0) ? ax[o] : 0.f;
        r[16 + o] += aa[o];
    }
#pragma unroll
    for (int j = 0; j < 24; j++)
        out[(size_t)n * 24 + j] = fmaxf(r[j], 0.f);
}

// ---- output head ----
__global__ void head_kernel(const float* __restrict__ x, const float* __restrict__ W,
                            const float* __restrict__ b, float* __restrict__ out, int N)
{
    int n = blockIdx.x * blockDim.x + threadIdx.x;
    if (n >= N) return;
    float l0 = b[0], l1 = b[1];
#pragma unroll
    for (int i = 0; i < 24; i++) {
        float xi = x[(size_t)n * 24 + i];
        l0 = fmaf(xi, W[i * 2 + 0], l0);
        l1 = fmaf(xi, W[i * 2 + 1], l1);
    }
    out[2 * (size_t)n + 0] = l0;
    out[2 * (size_t)n + 1] = l1;
    float m = fmaxf(l0, l1);
    float e0 = __expf(l0 - m), e1 = __expf(l1 - m);
    float s = e0 + e1;
    out[2 * (size_t)N + 2 * (size_t)n + 0] = e0 / s;
    out[2 * (size_t)N + 2 * (size_t)n + 1] = e1 / s;
}

extern "C" void kernel_launch(void* const* d_in, const int* in_sizes, int n_in,
                              void* d_out, int out_size, void* d_ws, size_t ws_size,
                              hipStream_t stream)
{
    const float* x_feat = (const float*)d_in[0];
    const int*   eidx   = (const int*)d_in[1];
    const float* eattr  = (const float*)d_in[2];
    const float* lpW = (const float*)d_in[3];
    const float* lpb = (const float*)d_in[4];
    const float* tW  = (const float*)d_in[5];
    const float* tb  = (const float*)d_in[6];
    const float* eW1 = (const float*)d_in[7];
    const float* eb1 = (const float*)d_in[8];
    const float* eW2 = (const float*)d_in[9];
    const float* eb2 = (const float*)d_in[10];
    const float* c1W = (const float*)d_in[11];
    const float* c1B = (const float*)d_in[12];
    const float* c1R = (const float*)d_in[13];
    const float* c1b = (const float*)d_in[14];
    const float* c2W = (const float*)d_in[15];
    const float* c2B = (const float*)d_in[16];
    const float* c2R = (const float*)d_in[17];
    const float* c2b = (const float*)d_in[18];
    const float* oW  = (const float*)d_in[19];
    const float* ob  = (const float*)d_in[20];

    int N = in_sizes[0] / 24;
    int E = in_sizes[1] / 2;
    const int* srcA = eidx;
    const int* dstA = eidx + E;

    char* wsb = (char*)d_ws;
    size_t off = 0;
    auto alloc = [&](size_t bytes) {
        off = (off + 255) & ~(size_t)255;
        void* p = wsb + off;
        off += bytes;
        return p;
    };
    unsigned short* Y    = (unsigned short*)alloc((size_t)N * 408 * 2);
    float* msg  = (float*)alloc((size_t)E * 24 * 4);
    unsigned short* er_s = (unsigned short*)alloc((size_t)E * 16 * 2);
    float* x16  = (float*)alloc((size_t)N * 16 * 4);
    float* x24a = (float*)alloc((size_t)N * 24 * 4);
    float* x24b = (float*)alloc((size_t)N * 24 * 4);
    int* ibase  = (int*)alloc(((size_t)2 * N + 2) * 4);  // cntS | degD | cursS | cursD (zeroed)
    int* cntS = ibase;
    int* degD = ibase + N;
    int* cursS = ibase + 2 * N;
    int* cursD = ibase + 2 * N + 1;
    int* offsD = (int*)alloc((size_t)N * 4);
    int* curD  = (int*)alloc((size_t)N * 4);
    int* offsS = (int*)alloc((size_t)N * 4);
    int* curS  = (int*)alloc((size_t)N * 4);
    int* eid_src = (int*)alloc((size_t)E * 4);
    int* srcnode = (int*)alloc((size_t)E * 4);
    int* eidm    = (int*)alloc((size_t)E * 4);

    dim3 blk(BS);
    int nb_nodes = (N + BS - 1) / BS;
    int nb_edges = (E + BS - 1) / BS;
    dim3 ygrid(nb_nodes, 17);

    hipMemsetAsync(ibase, 0, (2 * (size_t)N + 2) * 4, stream);

    prep_kernel<<<nb_nodes, blk, 0, stream>>>(x_feat, lpW, lpb, tW, tb, x16, N);

    deg2_kernel<<<nb_edges, blk, 0, stream>>>(srcA, dstA, cntS, degD, E);
    offsets2_kernel<<<nb_nodes, blk, 0, stream>>>(cntS, degD, offsS, curS, offsD, curD,
                                                  cursS, cursD, N);
    fill2_kernel<<<nb_edges, blk, 0, stream>>>(srcA, dstA, curS, curD,
                                               eid_src, srcnode, eidm, E);

    // ---- conv1 (computes er_s) ----
    ynode_kernel<16><<<ygrid, blk, 0, stream>>>(x16, c1W, c1B, Y, N);
    msg_kernel<true><<<nb_edges, blk, 0, stream>>>(srcnode, eid_src, eattr,
                                                   eW1, eb1, eW2, eb2, er_s, Y, msg, E);
    gather_kernel<16><<<nb_nodes, blk, 0, stream>>>(x16, msg, offsD, degD, eidm, c1R, c1b, x24a, N);

    // ---- conv2 (reuses er_s) ----
    ynode_kernel<24><<<ygrid, blk, 0, stream>>>(x24a, c2W, c2B, Y, N);
    msg_kernel<false><<<nb_edges, blk, 0, stream>>>(srcnode, eid_src, eattr,
                                                    eW1, eb1, eW2, eb2, er_s, Y, msg, E);
    gather_kernel<24><<<nb_nodes, blk, 0, stream>>>(x24a, msg, offsD, degD, eidm, c2R, c2b, x24b, N);

    head_kernel<<<nb_nodes, blk, 0, stream>>>(x24b, oW, ob, (float*)d_out, N);
}

// Round 6
// 440.986 us; speedup vs baseline: 3.1615x; 1.0603x over previous
//
#include <hip/hip_runtime.h>

#define BS 256

// ---------------- bf16 helpers ----------------
__device__ __forceinline__ unsigned short f2bf(float f) {
    unsigned x = __float_as_uint(f);
    return (unsigned short)((x + 0x7fffu + ((x >> 16) & 1u)) >> 16);
}
__device__ __forceinline__ void unpack8(uint4 v, float* d) {
    d[0] = __uint_as_float(v.x << 16); d[1] = __uint_as_float(v.x & 0xFFFF0000u);
    d[2] = __uint_as_float(v.y << 16); d[3] = __uint_as_float(v.y & 0xFFFF0000u);
    d[4] = __uint_as_float(v.z << 16); d[5] = __uint_as_float(v.z & 0xFFFF0000u);
    d[6] = __uint_as_float(v.w << 16); d[7] = __uint_as_float(v.w & 0xFFFF0000u);
}
// store 24 floats as 24 bf16 (48 B = 3x uint4)
__device__ __forceinline__ void st24bf(unsigned short* p, const float* r) {
    unsigned w[12];
#pragma unroll
    for (int j = 0; j < 12; j++)
        w[j] = (unsigned)f2bf(r[2 * j]) | ((unsigned)f2bf(r[2 * j + 1]) << 16);
    uint4* q = (uint4*)p;
    q[0] = make_uint4(w[0], w[1], w[2], w[3]);
    q[1] = make_uint4(w[4], w[5], w[6], w[7]);
    q[2] = make_uint4(w[8], w[9], w[10], w[11]);
}

// ---- node prep: x16 = relu(relu(x_feat @ lpW + lpb) @ tW + tb) ----
__global__ void prep_kernel(const float* __restrict__ xf,
                            const float* __restrict__ W1, const float* __restrict__ b1,
                            const float* __restrict__ W2, const float* __restrict__ b2,
                            float* __restrict__ x16, int N)
{
    int n = blockIdx.x * blockDim.x + threadIdx.x;
    bool valid = n < N;
    int nn = valid ? n : 0;
    float a[24];
#pragma unroll
    for (int i = 0; i < 24; i += 4)
        *(float4*)(a + i) = *(const float4*)(xf + (size_t)nn * 24 + i);
    float h[32];
#pragma unroll
    for (int j = 0; j < 32; j++) {
        float s = b1[j];
#pragma unroll
        for (int i = 0; i < 24; i++) s = fmaf(a[i], W1[i * 32 + j], s);
        h[j] = fmaxf(s, 0.f);
    }
    if (!valid) return;
#pragma unroll
    for (int j = 0; j < 16; j++) {
        float s = b2[j];
#pragma unroll
        for (int i = 0; i < 32; i++) s = fmaf(h[i], W2[i * 16 + j], s);
        x16[(size_t)n * 16 + j] = fmaxf(s, 0.f);
    }
}

// ---- CSR build (fused: both src and dst sides) ----
__global__ void deg2_kernel(const int* __restrict__ srcA, const int* __restrict__ dstA,
                            int* __restrict__ cntS, int* __restrict__ degD, int E)
{
    int i = blockIdx.x * blockDim.x + threadIdx.x;
    if (i < E) {
        atomicAdd(&cntS[srcA[i]], 1);
        atomicAdd(&degD[dstA[i]], 1);
    }
}
// wave-scan offsets: 1 cursor atomic per wave instead of per thread
__global__ void offsets2_kernel(const int* __restrict__ cntS, const int* __restrict__ degD,
                                int* __restrict__ offsS, int* __restrict__ curS,
                                int* __restrict__ offsD, int* __restrict__ curD,
                                int* __restrict__ cursS, int* __restrict__ cursD, int N)
{
    int n = blockIdx.x * blockDim.x + threadIdx.x;
    int lane = threadIdx.x & 63;
    bool valid = n < N;
    int dS = valid ? cntS[n] : 0;
    int dD = valid ? degD[n] : 0;
    int sS = dS, sD = dD;
#pragma unroll
    for (int o = 1; o < 64; o <<= 1) {
        int tS = __shfl_up(sS, o);
        int tD = __shfl_up(sD, o);
        if (lane >= o) { sS += tS; sD += tD; }
    }
    int totS = __shfl(sS, 63);
    int totD = __shfl(sD, 63);
    int baseS = 0, baseD = 0;
    if (lane == 63) {
        baseS = atomicAdd(cursS, totS);
        baseD = atomicAdd(cursD, totD);
    }
    baseS = __shfl(baseS, 63);
    baseD = __shfl(baseD, 63);
    if (valid) {
        int oS = baseS + sS - dS;
        int oD = baseD + sD - dD;
        offsS[n] = oS; curS[n] = oS;
        offsD[n] = oD; curD[n] = oD;
    }
}
// fused fill: sorted src position p (msg row); dst list stores p directly
__global__ void fill2_kernel(const int* __restrict__ srcA, const int* __restrict__ dstA,
                             int* __restrict__ curS, int* __restrict__ curD,
                             int* __restrict__ eid_src, int* __restrict__ srcnode,
                             int* __restrict__ eidm, int E)
{
    int e = blockIdx.x * blockDim.x + threadIdx.x;
    if (e < E) {
        int s = srcA[e];
        int p = atomicAdd(&curS[s], 1);
        eid_src[p] = e;
        srcnode[p] = s;
        int q = atomicAdd(&curD[dstA[e]], 1);
        eidm[q] = p;
    }
}

// ---- per-(node, k-slot) Y precompute: grid.y = 17 slots; slot16 = x@B ----
template <int IN>
__global__ __launch_bounds__(BS) void ynode_kernel(const float* __restrict__ x,
                                                   const float* __restrict__ W,  // [3][16][IN*8]
                                                   const float* __restrict__ B,  // [3][IN*8]
                                                   unsigned short* __restrict__ Y, int N)
{
    int n = blockIdx.x * BS + threadIdx.x;
    int k = blockIdx.y;            // 0..16, block-uniform
    bool valid = n < N;
    int nn = valid ? n : 0;
    float xv[IN];
#pragma unroll
    for (int i = 0; i < IN; i += 4)
        *(float4*)(xv + i) = *(const float4*)(x + (size_t)nn * IN + i);

    float r[24];
#pragma unroll
    for (int j = 0; j < 24; j++) r[j] = 0.f;

    if (k < 16) {
        const float* w = W + (size_t)k * (IN * 8);
#pragma unroll
        for (int a = 0; a < 3; a++) {
            const float* wa = w + (size_t)a * (16 * IN * 8);
#pragma unroll
            for (int i = 0; i < IN; i++) {
                float xi = xv[i];
#pragma unroll
                for (int o = 0; o < 8; o++)
                    r[a * 8 + o] = fmaf(xi, wa[i * 8 + o], r[a * 8 + o]);
            }
        }
    } else {
#pragma unroll
        for (int a = 0; a < 3; a++) {
            const float* ba = B + (size_t)a * (IN * 8);
#pragma unroll
            for (int i = 0; i < IN; i++) {
                float xi = xv[i];
#pragma unroll
                for (int o = 0; o < 8; o++)
                    r[a * 8 + o] = fmaf(xi, ba[i * 8 + o], r[a * 8 + o]);
            }
        }
    }
    if (valid) st24bf(Y + (size_t)n * 408 + k * 24, r);
}

// ---- edge trunk only: er_s[p] = sigmoid(relu(eattr[e] @ W1 + b1) @ W2 + b2) ----
__global__ __launch_bounds__(BS) void er_kernel(
    const int* __restrict__ eid_src, const float* __restrict__ eattr,
    const float* __restrict__ eW1, const float* __restrict__ eb1,
    const float* __restrict__ eW2, const float* __restrict__ eb2,
    unsigned short* __restrict__ er_s, int E)
{
    int p = blockIdx.x * BS + threadIdx.x;
    if (p >= E) return;
    int e = eid_src[p];
    float ea[16];
#pragma unroll
    for (int i = 0; i < 16; i += 4)
        *(float4*)(ea + i) = *(const float4*)(eattr + (size_t)e * 16 + i);
    float h[32];
#pragma unroll
    for (int j = 0; j < 32; j++) {
        float s = eb1[j];
#pragma unroll
        for (int i = 0; i < 16; i++) s = fmaf(ea[i], eW1[i * 32 + j], s);
        h[j] = fmaxf(s, 0.f);
    }
    float er[16];
#pragma unroll
    for (int j = 0; j < 16; j++) {
        float s = eb2[j];
#pragma unroll
        for (int i = 0; i < 32; i++) s = fmaf(h[i], eW2[i * 16 + j], s);
        er[j] = 1.f / (1.f + __expf(-s));
    }
    unsigned w[8];
#pragma unroll
    for (int j = 0; j < 8; j++)
        w[j] = (unsigned)f2bf(er[2 * j]) | ((unsigned)f2bf(er[2 * j + 1]) << 16);
    uint4* q = (uint4*)(er_s + (size_t)p * 16);
    q[0] = make_uint4(w[0], w[1], w[2], w[3]);
    q[1] = make_uint4(w[4], w[5], w[6], w[7]);
}

// ---- per-(edge, 8-col part) msg: 3 threads per edge, part j handles cols j*8..j*8+7 ----
__global__ __launch_bounds__(BS) void msg_kernel(
    const int* __restrict__ srcnode,
    const unsigned short* __restrict__ er_s,   // [E][16] bf16, sorted order
    const unsigned short* __restrict__ Y,
    float* __restrict__ msg, int E)
{
    int tid = blockIdx.x * BS + threadIdx.x;
    int p = tid / 3;
    int j = tid - p * 3;
    if (p >= E) return;

    float er[16];
    {
        const uint4* eu = (const uint4*)(er_s + (size_t)p * 16);
        unpack8(eu[0], er);
        unpack8(eu[1], er + 8);
    }

    int s = srcnode[p];
    const uint4* yu = (const uint4*)(Y + (size_t)s * 408) + j;

    float acc[8];
    unpack8(yu[48], acc);         // bias slot (orig index 48+j)
#pragma unroll
    for (int k = 0; k < 16; k++) {
        float t[8];
        unpack8(yu[k * 3], t);
        float ek = er[k];
#pragma unroll
        for (int q = 0; q < 8; q++) acc[q] = fmaf(ek, t[q], acc[q]);
    }
    float* m = msg + (size_t)p * 24 + j * 8;
    *(float4*)(m)     = make_float4(acc[0], acc[1], acc[2], acc[3]);
    *(float4*)(m + 4) = make_float4(acc[4], acc[5], acc[6], acc[7]);
}

// ---- per-(node, aggregator) gather + root transform + relu ----
template <int IN>
__global__ void gather_kernel(const float* __restrict__ x,
                              const float* __restrict__ msg,
                              const int* __restrict__ offs,
                              const int* __restrict__ degi,
                              const int* __restrict__ eidm,
                              const float* __restrict__ rootW,  // [3][IN][8]
                              const float* __restrict__ bias,   // [3][8]
                              float* __restrict__ out, int N)
{
    int tid = blockIdx.x * blockDim.x + threadIdx.x;
    int n = tid / 3;
    int a = tid - n * 3;
    if (n >= N) return;

    float as[8], am[8];
#pragma unroll
    for (int o = 0; o < 8; o++) { as[o] = 0.f; am[o] = -3.402823466e38f; }

    int off = offs[n];
    int d = degi[n];
    for (int j = 0; j < d; j++) {
        int r = eidm[off + j];
        const float* m = msg + (size_t)r * 24 + a * 8;
        float4 m0 = *(const float4*)(m);
        float4 m1 = *(const float4*)(m + 4);
        as[0] += m0.x; as[1] += m0.y; as[2] += m0.z; as[3] += m0.w;
        as[4] += m1.x; as[5] += m1.y; as[6] += m1.z; as[7] += m1.w;
        am[0] = fmaxf(am[0], m0.x); am[1] = fmaxf(am[1], m0.y);
        am[2] = fmaxf(am[2], m0.z); am[3] = fmaxf(am[3], m0.w);
        am[4] = fmaxf(am[4], m1.x); am[5] = fmaxf(am[5], m1.y);
        am[6] = fmaxf(am[6], m1.z); am[7] = fmaxf(am[7], m1.w);
    }

    float xv[IN];
#pragma unroll
    for (int i = 0; i < IN; i += 4)
        *(float4*)(xv + i) = *(const float4*)(x + (size_t)n * IN + i);

    float inv = 1.f / fmaxf((float)d, 1.f);
    float rr[8];
#pragma unroll
    for (int o = 0; o < 8; o++) {
        float agg = (a == 0) ? as[o] * inv
                  : (a == 1) ? ((d > 0) ? am[o] : 0.f)
                  : as[o];
        float s = bias[a * 8 + o];
#pragma unroll
        for (int i = 0; i < IN; i++) s = fmaf(xv[i], rootW[(a * IN + i) * 8 + o], s);
        rr[o] = fmaxf(s + agg, 0.f);
    }
    float* po = out + (size_t)n * 24 + a * 8;
    *(float4*)(po)     = make_float4(rr[0], rr[1], rr[2], rr[3]);
    *(float4*)(po + 4) = make_float4(rr[4], rr[5], rr[6], rr[7]);
}

// ---- output head ----
__global__ void head_kernel(const float* __restrict__ x, const float* __restrict__ W,
                            const float* __restrict__ b, float* __restrict__ out, int N)
{
    int n = blockIdx.x * blockDim.x + threadIdx.x;
    if (n >= N) return;
    float l0 = b[0], l1 = b[1];
#pragma unroll
    for (int i = 0; i < 24; i++) {
        float xi = x[(size_t)n * 24 + i];
        l0 = fmaf(xi, W[i * 2 + 0], l0);
        l1 = fmaf(xi, W[i * 2 + 1], l1);
    }
    out[2 * (size_t)n + 0] = l0;
    out[2 * (size_t)n + 1] = l1;
    float m = fmaxf(l0, l1);
    float e0 = __expf(l0 - m), e1 = __expf(l1 - m);
    float s = e0 + e1;
    out[2 * (size_t)N + 2 * (size_t)n + 0] = e0 / s;
    out[2 * (size_t)N + 2 * (size_t)n + 1] = e1 / s;
}

extern "C" void kernel_launch(void* const* d_in, const int* in_sizes, int n_in,
                              void* d_out, int out_size, void* d_ws, size_t ws_size,
                              hipStream_t stream)
{
    const float* x_feat = (const float*)d_in[0];
    const int*   eidx   = (const int*)d_in[1];
    const float* eattr  = (const float*)d_in[2];
    const float* lpW = (const float*)d_in[3];
    const float* lpb = (const float*)d_in[4];
    const float* tW  = (const float*)d_in[5];
    const float* tb  = (const float*)d_in[6];
    const float* eW1 = (const float*)d_in[7];
    const float* eb1 = (const float*)d_in[8];
    const float* eW2 = (const float*)d_in[9];
    const float* eb2 = (const float*)d_in[10];
    const float* c1W = (const float*)d_in[11];
    const float* c1B = (const float*)d_in[12];
    const float* c1R = (const float*)d_in[13];
    const float* c1b = (const float*)d_in[14];
    const float* c2W = (const float*)d_in[15];
    const float* c2B = (const float*)d_in[16];
    const float* c2R = (const float*)d_in[17];
    const float* c2b = (const float*)d_in[18];
    const float* oW  = (const float*)d_in[19];
    const float* ob  = (const float*)d_in[20];

    int N = in_sizes[0] / 24;
    int E = in_sizes[1] / 2;
    const int* srcA = eidx;
    const int* dstA = eidx + E;

    char* wsb = (char*)d_ws;
    size_t off = 0;
    auto alloc = [&](size_t bytes) {
        off = (off + 255) & ~(size_t)255;
        void* p = wsb + off;
        off += bytes;
        return p;
    };
    unsigned short* Y    = (unsigned short*)alloc((size_t)N * 408 * 2);
    float* msg  = (float*)alloc((size_t)E * 24 * 4);
    unsigned short* er_s = (unsigned short*)alloc((size_t)E * 16 * 2);
    float* x16  = (float*)alloc((size_t)N * 16 * 4);
    float* x24a = (float*)alloc((size_t)N * 24 * 4);
    float* x24b = (float*)alloc((size_t)N * 24 * 4);
    int* ibase  = (int*)alloc(((size_t)2 * N + 2) * 4);  // cntS | degD | cursS | cursD (zeroed)
    int* cntS = ibase;
    int* degD = ibase + N;
    int* cursS = ibase + 2 * N;
    int* cursD = ibase + 2 * N + 1;
    int* offsD = (int*)alloc((size_t)N * 4);
    int* curD  = (int*)alloc((size_t)N * 4);
    int* offsS = (int*)alloc((size_t)N * 4);
    int* curS  = (int*)alloc((size_t)N * 4);
    int* eid_src = (int*)alloc((size_t)E * 4);
    int* srcnode = (int*)alloc((size_t)E * 4);
    int* eidm    = (int*)alloc((size_t)E * 4);

    dim3 blk(BS);
    int nb_nodes = (N + BS - 1) / BS;
    int nb_edges = (E + BS - 1) / BS;
    int nb_msg   = (3 * E + BS - 1) / BS;
    int nb_gath  = (3 * N + BS - 1) / BS;
    dim3 ygrid(nb_nodes, 17);

    hipMemsetAsync(ibase, 0, (2 * (size_t)N + 2) * 4, stream);

    prep_kernel<<<nb_nodes, blk, 0, stream>>>(x_feat, lpW, lpb, tW, tb, x16, N);

    deg2_kernel<<<nb_edges, blk, 0, stream>>>(srcA, dstA, cntS, degD, E);
    offsets2_kernel<<<nb_nodes, blk, 0, stream>>>(cntS, degD, offsS, curS, offsD, curD,
                                                  cursS, cursD, N);
    fill2_kernel<<<nb_edges, blk, 0, stream>>>(srcA, dstA, curS, curD,
                                               eid_src, srcnode, eidm, E);

    er_kernel<<<nb_edges, blk, 0, stream>>>(eid_src, eattr, eW1, eb1, eW2, eb2, er_s, E);

    // ---- conv1 ----
    ynode_kernel<16><<<ygrid, blk, 0, stream>>>(x16, c1W, c1B, Y, N);
    msg_kernel<<<nb_msg, blk, 0, stream>>>(srcnode, er_s, Y, msg, E);
    gather_kernel<16><<<nb_gath, blk, 0, stream>>>(x16, msg, offsD, degD, eidm, c1R, c1b, x24a, N);

    // ---- conv2 ----
    ynode_kernel<24><<<ygrid, blk, 0, stream>>>(x24a, c2W, c2B, Y, N);
    msg_kernel<<<nb_msg, blk, 0, stream>>>(srcnode, er_s, Y, msg, E);
    gather_kernel<24><<<nb_gath, blk, 0, stream>>>(x24a, msg, offsD, degD, eidm, c2R, c2b, x24b, N);

    head_kernel<<<nb_nodes, blk, 0, stream>>>(x24b, oW, ob, (float*)d_out, N);
}

// Round 7
// 431.457 us; speedup vs baseline: 3.2313x; 1.0221x over previous
//
#include <hip/hip_runtime.h>

#define BS 256

// ---------------- bf16 helpers ----------------
__device__ __forceinline__ unsigned short f2bf(float f) {
    unsigned x = __float_as_uint(f);
    return (unsigned short)((x + 0x7fffu + ((x >> 16) & 1u)) >> 16);
}
__device__ __forceinline__ void unpack8(uint4 v, float* d) {
    d[0] = __uint_as_float(v.x << 16); d[1] = __uint_as_float(v.x & 0xFFFF0000u);
    d[2] = __uint_as_float(v.y << 16); d[3] = __uint_as_float(v.y & 0xFFFF0000u);
    d[4] = __uint_as_float(v.z << 16); d[5] = __uint_as_float(v.z & 0xFFFF0000u);
    d[6] = __uint_as_float(v.w << 16); d[7] = __uint_as_float(v.w & 0xFFFF0000u);
}
// store 24 floats as 24 bf16 (48 B = 3x uint4)
__device__ __forceinline__ void st24bf(unsigned short* p, const float* r) {
    unsigned w[12];
#pragma unroll
    for (int j = 0; j < 12; j++)
        w[j] = (unsigned)f2bf(r[2 * j]) | ((unsigned)f2bf(r[2 * j + 1]) << 16);
    uint4* q = (uint4*)p;
    q[0] = make_uint4(w[0], w[1], w[2], w[3]);
    q[1] = make_uint4(w[4], w[5], w[6], w[7]);
    q[2] = make_uint4(w[8], w[9], w[10], w[11]);
}

// ---- node prep: x16 = relu(relu(x_feat @ lpW + lpb) @ tW + tb) ----
__global__ void prep_kernel(const float* __restrict__ xf,
                            const float* __restrict__ W1, const float* __restrict__ b1,
                            const float* __restrict__ W2, const float* __restrict__ b2,
                            float* __restrict__ x16, int N)
{
    int n = blockIdx.x * blockDim.x + threadIdx.x;
    bool valid = n < N;
    int nn = valid ? n : 0;
    float a[24];
#pragma unroll
    for (int i = 0; i < 24; i += 4)
        *(float4*)(a + i) = *(const float4*)(xf + (size_t)nn * 24 + i);
    float h[32];
#pragma unroll
    for (int j = 0; j < 32; j++) {
        float s = b1[j];
#pragma unroll
        for (int i = 0; i < 24; i++) s = fmaf(a[i], W1[i * 32 + j], s);
        h[j] = fmaxf(s, 0.f);
    }
    if (!valid) return;
#pragma unroll
    for (int j = 0; j < 16; j++) {
        float s = b2[j];
#pragma unroll
        for (int i = 0; i < 32; i++) s = fmaf(h[i], W2[i * 16 + j], s);
        x16[(size_t)n * 16 + j] = fmaxf(s, 0.f);
    }
}

// ---- CSR build (fused: both src and dst sides) ----
__global__ void deg2_kernel(const int* __restrict__ srcA, const int* __restrict__ dstA,
                            int* __restrict__ cntS, int* __restrict__ degD, int E)
{
    int i = blockIdx.x * blockDim.x + threadIdx.x;
    if (i < E) {
        atomicAdd(&cntS[srcA[i]], 1);
        atomicAdd(&degD[dstA[i]], 1);
    }
}
// wave-scan offsets: 1 cursor atomic per wave instead of per thread
__global__ void offsets2_kernel(const int* __restrict__ cntS, const int* __restrict__ degD,
                                int* __restrict__ offsS, int* __restrict__ curS,
                                int* __restrict__ offsD, int* __restrict__ curD,
                                int* __restrict__ cursS, int* __restrict__ cursD, int N)
{
    int n = blockIdx.x * blockDim.x + threadIdx.x;
    int lane = threadIdx.x & 63;
    bool valid = n < N;
    int dS = valid ? cntS[n] : 0;
    int dD = valid ? degD[n] : 0;
    int sS = dS, sD = dD;
#pragma unroll
    for (int o = 1; o < 64; o <<= 1) {
        int tS = __shfl_up(sS, o);
        int tD = __shfl_up(sD, o);
        if (lane >= o) { sS += tS; sD += tD; }
    }
    int totS = __shfl(sS, 63);
    int totD = __shfl(sD, 63);
    int baseS = 0, baseD = 0;
    if (lane == 63) {
        baseS = atomicAdd(cursS, totS);
        baseD = atomicAdd(cursD, totD);
    }
    baseS = __shfl(baseS, 63);
    baseD = __shfl(baseD, 63);
    if (valid) {
        int oS = baseS + sS - dS;
        int oD = baseD + sD - dD;
        offsS[n] = oS; curS[n] = oS;
        offsD[n] = oD; curD[n] = oD;
    }
}
// fused fill: src-sorted position p (compute row), dst-sorted position q (msg row)
__global__ void fill2_kernel(const int* __restrict__ srcA, const int* __restrict__ dstA,
                             int* __restrict__ curS, int* __restrict__ curD,
                             int* __restrict__ eid_src, int* __restrict__ srcnode,
                             int* __restrict__ p2q, int E)
{
    int e = blockIdx.x * blockDim.x + threadIdx.x;
    if (e < E) {
        int s = srcA[e];
        int p = atomicAdd(&curS[s], 1);
        eid_src[p] = e;
        srcnode[p] = s;
        int q = atomicAdd(&curD[dstA[e]], 1);
        p2q[p] = q;
    }
}

// ---- per-(node, k-slot) Y precompute: grid.y = 17 slots; slot16 = x@B ----
template <int IN>
__global__ __launch_bounds__(BS) void ynode_kernel(const float* __restrict__ x,
                                                   const float* __restrict__ W,  // [3][16][IN*8]
                                                   const float* __restrict__ B,  // [3][IN*8]
                                                   unsigned short* __restrict__ Y, int N)
{
    int n = blockIdx.x * BS + threadIdx.x;
    int k = blockIdx.y;            // 0..16, block-uniform
    bool valid = n < N;
    int nn = valid ? n : 0;
    float xv[IN];
#pragma unroll
    for (int i = 0; i < IN; i += 4)
        *(float4*)(xv + i) = *(const float4*)(x + (size_t)nn * IN + i);

    float r[24];
#pragma unroll
    for (int j = 0; j < 24; j++) r[j] = 0.f;

    if (k < 16) {
        const float* w = W + (size_t)k * (IN * 8);
#pragma unroll
        for (int a = 0; a < 3; a++) {
            const float* wa = w + (size_t)a * (16 * IN * 8);
#pragma unroll
            for (int i = 0; i < IN; i++) {
                float xi = xv[i];
#pragma unroll
                for (int o = 0; o < 8; o++)
                    r[a * 8 + o] = fmaf(xi, wa[i * 8 + o], r[a * 8 + o]);
            }
        }
    } else {
#pragma unroll
        for (int a = 0; a < 3; a++) {
            const float* ba = B + (size_t)a * (IN * 8);
#pragma unroll
            for (int i = 0; i < IN; i++) {
                float xi = xv[i];
#pragma unroll
                for (int o = 0; o < 8; o++)
                    r[a * 8 + o] = fmaf(xi, ba[i * 8 + o], r[a * 8 + o]);
            }
        }
    }
    if (valid) st24bf(Y + (size_t)n * 408 + k * 24, r);
}

// ---- edge trunk only: er_s[p] = sigmoid(relu(eattr[e] @ W1 + b1) @ W2 + b2) ----
__global__ __launch_bounds__(BS) void er_kernel(
    const int* __restrict__ eid_src, const float* __restrict__ eattr,
    const float* __restrict__ eW1, const float* __restrict__ eb1,
    const float* __restrict__ eW2, const float* __restrict__ eb2,
    unsigned short* __restrict__ er_s, int E)
{
    int p = blockIdx.x * BS + threadIdx.x;
    if (p >= E) return;
    int e = eid_src[p];
    float ea[16];
#pragma unroll
    for (int i = 0; i < 16; i += 4)
        *(float4*)(ea + i) = *(const float4*)(eattr + (size_t)e * 16 + i);
    float h[32];
#pragma unroll
    for (int j = 0; j < 32; j++) {
        float s = eb1[j];
#pragma unroll
        for (int i = 0; i < 16; i++) s = fmaf(ea[i], eW1[i * 32 + j], s);
        h[j] = fmaxf(s, 0.f);
    }
    float er[16];
#pragma unroll
    for (int j = 0; j < 16; j++) {
        float s = eb2[j];
#pragma unroll
        for (int i = 0; i < 32; i++) s = fmaf(h[i], eW2[i * 16 + j], s);
        er[j] = 1.f / (1.f + __expf(-s));
    }
    unsigned w[8];
#pragma unroll
    for (int j = 0; j < 8; j++)
        w[j] = (unsigned)f2bf(er[2 * j]) | ((unsigned)f2bf(er[2 * j + 1]) << 16);
    uint4* q = (uint4*)(er_s + (size_t)p * 16);
    q[0] = make_uint4(w[0], w[1], w[2], w[3]);
    q[1] = make_uint4(w[4], w[5], w[6], w[7]);
}

// ---- per-(edge, 8-col part) msg: compute in src order (Y locality), write at dst slot ----
__global__ __launch_bounds__(BS) void msg_kernel(
    const int* __restrict__ srcnode,
    const int* __restrict__ p2q,
    const unsigned short* __restrict__ er_s,   // [E][16] bf16, src-sorted
    const unsigned short* __restrict__ Y,
    float* __restrict__ msg, int E)
{
    int tid = blockIdx.x * BS + threadIdx.x;
    int p = tid / 3;
    int j = tid - p * 3;
    if (p >= E) return;

    float er[16];
    {
        const uint4* eu = (const uint4*)(er_s + (size_t)p * 16);
        unpack8(eu[0], er);
        unpack8(eu[1], er + 8);
    }

    int s = srcnode[p];
    const uint4* yu = (const uint4*)(Y + (size_t)s * 408) + j;

    float acc[8];
    unpack8(yu[48], acc);         // bias slot (orig index 48+j)
#pragma unroll
    for (int k = 0; k < 16; k++) {
        float t[8];
        unpack8(yu[k * 3], t);
        float ek = er[k];
#pragma unroll
        for (int q = 0; q < 8; q++) acc[q] = fmaf(ek, t[q], acc[q]);
    }
    int q = p2q[p];
    float* m = msg + (size_t)q * 24 + j * 8;
    *(float4*)(m)     = make_float4(acc[0], acc[1], acc[2], acc[3]);
    *(float4*)(m + 4) = make_float4(acc[4], acc[5], acc[6], acc[7]);
}

// ---- per-(node, aggregator) gather: msg rows are contiguous per node (dst-sorted) ----
template <int IN>
__global__ void gather_kernel(const float* __restrict__ x,
                              const float* __restrict__ msg,
                              const int* __restrict__ offs,
                              const int* __restrict__ degi,
                              const float* __restrict__ rootW,  // [3][IN][8]
                              const float* __restrict__ bias,   // [3][8]
                              float* __restrict__ out, int N)
{
    int tid = blockIdx.x * blockDim.x + threadIdx.x;
    int n = tid / 3;
    int a = tid - n * 3;
    if (n >= N) return;

    float as[8], am[8];
#pragma unroll
    for (int o = 0; o < 8; o++) { as[o] = 0.f; am[o] = -3.402823466e38f; }

    int off = offs[n];
    int d = degi[n];
    const float* mrow = msg + (size_t)off * 24 + a * 8;
    for (int j = 0; j < d; j++) {
        float4 m0 = *(const float4*)(mrow);
        float4 m1 = *(const float4*)(mrow + 4);
        mrow += 24;
        as[0] += m0.x; as[1] += m0.y; as[2] += m0.z; as[3] += m0.w;
        as[4] += m1.x; as[5] += m1.y; as[6] += m1.z; as[7] += m1.w;
        am[0] = fmaxf(am[0], m0.x); am[1] = fmaxf(am[1], m0.y);
        am[2] = fmaxf(am[2], m0.z); am[3] = fmaxf(am[3], m0.w);
        am[4] = fmaxf(am[4], m1.x); am[5] = fmaxf(am[5], m1.y);
        am[6] = fmaxf(am[6], m1.z); am[7] = fmaxf(am[7], m1.w);
    }

    float xv[IN];
#pragma unroll
    for (int i = 0; i < IN; i += 4)
        *(float4*)(xv + i) = *(const float4*)(x + (size_t)n * IN + i);

    float inv = 1.f / fmaxf((float)d, 1.f);
    float rr[8];
#pragma unroll
    for (int o = 0; o < 8; o++) {
        float agg = (a == 0) ? as[o] * inv
                  : (a == 1) ? ((d > 0) ? am[o] : 0.f)
                  : as[o];
        float s = bias[a * 8 + o];
#pragma unroll
        for (int i = 0; i < IN; i++) s = fmaf(xv[i], rootW[(a * IN + i) * 8 + o], s);
        rr[o] = fmaxf(s + agg, 0.f);
    }
    float* po = out + (size_t)n * 24 + a * 8;
    *(float4*)(po)     = make_float4(rr[0], rr[1], rr[2], rr[3]);
    *(float4*)(po + 4) = make_float4(rr[4], rr[5], rr[6], rr[7]);
}

// ---- output head ----
__global__ void head_kernel(const float* __restrict__ x, const float* __restrict__ W,
                            const float* __restrict__ b, float* __restrict__ out, int N)
{
    int n = blockIdx.x * blockDim.x + threadIdx.x;
    if (n >= N) return;
    float l0 = b[0], l1 = b[1];
#pragma unroll
    for (int i = 0; i < 24; i++) {
        float xi = x[(size_t)n * 24 + i];
        l0 = fmaf(xi, W[i * 2 + 0], l0);
        l1 = fmaf(xi, W[i * 2 + 1], l1);
    }
    out[2 * (size_t)n + 0] = l0;
    out[2 * (size_t)n + 1] = l1;
    float m = fmaxf(l0, l1);
    float e0 = __expf(l0 - m), e1 = __expf(l1 - m);
    float s = e0 + e1;
    out[2 * (size_t)N + 2 * (size_t)n + 0] = e0 / s;
    out[2 * (size_t)N + 2 * (size_t)n + 1] = e1 / s;
}

extern "C" void kernel_launch(void* const* d_in, const int* in_sizes, int n_in,
                              void* d_out, int out_size, void* d_ws, size_t ws_size,
                              hipStream_t stream)
{
    const float* x_feat = (const float*)d_in[0];
    const int*   eidx   = (const int*)d_in[1];
    const float* eattr  = (const float*)d_in[2];
    const float* lpW = (const float*)d_in[3];
    const float* lpb = (const float*)d_in[4];
    const float* tW  = (const float*)d_in[5];
    const float* tb  = (const float*)d_in[6];
    const float* eW1 = (const float*)d_in[7];
    const float* eb1 = (const float*)d_in[8];
    const float* eW2 = (const float*)d_in[9];
    const float* eb2 = (const float*)d_in[10];
    const float* c1W = (const float*)d_in[11];
    const float* c1B = (const float*)d_in[12];
    const float* c1R = (const float*)d_in[13];
    const float* c1b = (const float*)d_in[14];
    const float* c2W = (const float*)d_in[15];
    const float* c2B = (const float*)d_in[16];
    const float* c2R = (const float*)d_in[17];
    const float* c2b = (const float*)d_in[18];
    const float* oW  = (const float*)d_in[19];
    const float* ob  = (const float*)d_in[20];

    int N = in_sizes[0] / 24;
    int E = in_sizes[1] / 2;
    const int* srcA = eidx;
    const int* dstA = eidx + E;

    char* wsb = (char*)d_ws;
    size_t off = 0;
    auto alloc = [&](size_t bytes) {
        off = (off + 255) & ~(size_t)255;
        void* p = wsb + off;
        off += bytes;
        return p;
    };
    unsigned short* Y    = (unsigned short*)alloc((size_t)N * 408 * 2);
    float* msg  = (float*)alloc((size_t)E * 24 * 4);
    unsigned short* er_s = (unsigned short*)alloc((size_t)E * 16 * 2);
    float* x16  = (float*)alloc((size_t)N * 16 * 4);
    float* x24a = (float*)alloc((size_t)N * 24 * 4);
    float* x24b = (float*)alloc((size_t)N * 24 * 4);
    int* ibase  = (int*)alloc(((size_t)2 * N + 2) * 4);  // cntS | degD | cursS | cursD (zeroed)
    int* cntS = ibase;
    int* degD = ibase + N;
    int* cursS = ibase + 2 * N;
    int* cursD = ibase + 2 * N + 1;
    int* offsD = (int*)alloc((size_t)N * 4);
    int* curD  = (int*)alloc((size_t)N * 4);
    int* offsS = (int*)alloc((size_t)N * 4);
    int* curS  = (int*)alloc((size_t)N * 4);
    int* eid_src = (int*)alloc((size_t)E * 4);
    int* srcnode = (int*)alloc((size_t)E * 4);
    int* p2q     = (int*)alloc((size_t)E * 4);

    dim3 blk(BS);
    int nb_nodes = (N + BS - 1) / BS;
    int nb_edges = (E + BS - 1) / BS;
    int nb_msg   = (3 * E + BS - 1) / BS;
    int nb_gath  = (3 * N + BS - 1) / BS;
    dim3 ygrid(nb_nodes, 17);

    hipMemsetAsync(ibase, 0, (2 * (size_t)N + 2) * 4, stream);

    prep_kernel<<<nb_nodes, blk, 0, stream>>>(x_feat, lpW, lpb, tW, tb, x16, N);

    deg2_kernel<<<nb_edges, blk, 0, stream>>>(srcA, dstA, cntS, degD, E);
    offsets2_kernel<<<nb_nodes, blk, 0, stream>>>(cntS, degD, offsS, curS, offsD, curD,
                                                  cursS, cursD, N);
    fill2_kernel<<<nb_edges, blk, 0, stream>>>(srcA, dstA, curS, curD,
                                               eid_src, srcnode, p2q, E);

    er_kernel<<<nb_edges, blk, 0, stream>>>(eid_src, eattr, eW1, eb1, eW2, eb2, er_s, E);

    // ---- conv1 ----
    ynode_kernel<16><<<ygrid, blk, 0, stream>>>(x16, c1W, c1B, Y, N);
    msg_kernel<<<nb_msg, blk, 0, stream>>>(srcnode, p2q, er_s, Y, msg, E);
    gather_kernel<16><<<nb_gath, blk, 0, stream>>>(x16, msg, offsD, degD, c1R, c1b, x24a, N);

    // ---- conv2 ----
    ynode_kernel<24><<<ygrid, blk, 0, stream>>>(x24a, c2W, c2B, Y, N);
    msg_kernel<<<nb_msg, blk, 0, stream>>>(srcnode, p2q, er_s, Y, msg, E);
    gather_kernel<24><<<nb_gath, blk, 0, stream>>>(x24a, msg, offsD, degD, c2R, c2b, x24b, N);

    head_kernel<<<nb_nodes, blk, 0, stream>>>(x24b, oW, ob, (float*)d_out, N);
}

// Round 8
// 421.836 us; speedup vs baseline: 3.3050x; 1.0228x over previous
//
#include <hip/hip_runtime.h>

#define BS 256

// ---------------- bf16 helpers ----------------
__device__ __forceinline__ unsigned short f2bf(float f) {
    unsigned x = __float_as_uint(f);
    return (unsigned short)((x + 0x7fffu + ((x >> 16) & 1u)) >> 16);
}
__device__ __forceinline__ void unpack8(uint4 v, float* d) {
    d[0] = __uint_as_float(v.x << 16); d[1] = __uint_as_float(v.x & 0xFFFF0000u);
    d[2] = __uint_as_float(v.y << 16); d[3] = __uint_as_float(v.y & 0xFFFF0000u);
    d[4] = __uint_as_float(v.z << 16); d[5] = __uint_as_float(v.z & 0xFFFF0000u);
    d[6] = __uint_as_float(v.w << 16); d[7] = __uint_as_float(v.w & 0xFFFF0000u);
}
// store 24 floats as 24 bf16 (48 B = 3x uint4)
__device__ __forceinline__ void st24bf(unsigned short* p, const float* r) {
    unsigned w[12];
#pragma unroll
    for (int j = 0; j < 12; j++)
        w[j] = (unsigned)f2bf(r[2 * j]) | ((unsigned)f2bf(r[2 * j + 1]) << 16);
    uint4* q = (uint4*)p;
    q[0] = make_uint4(w[0], w[1], w[2], w[3]);
    q[1] = make_uint4(w[4], w[5], w[6], w[7]);
    q[2] = make_uint4(w[8], w[9], w[10], w[11]);
}

// ---- node prep: x16 = relu(relu(x_feat @ lpW + lpb) @ tW + tb) ----
__global__ void prep_kernel(const float* __restrict__ xf,
                            const float* __restrict__ W1, const float* __restrict__ b1,
                            const float* __restrict__ W2, const float* __restrict__ b2,
                            float* __restrict__ x16, int N)
{
    int n = blockIdx.x * blockDim.x + threadIdx.x;
    bool valid = n < N;
    int nn = valid ? n : 0;
    float a[24];
#pragma unroll
    for (int i = 0; i < 24; i += 4)
        *(float4*)(a + i) = *(const float4*)(xf + (size_t)nn * 24 + i);
    float h[32];
#pragma unroll
    for (int j = 0; j < 32; j++) {
        float s = b1[j];
#pragma unroll
        for (int i = 0; i < 24; i++) s = fmaf(a[i], W1[i * 32 + j], s);
        h[j] = fmaxf(s, 0.f);
    }
    if (!valid) return;
#pragma unroll
    for (int j = 0; j < 16; j++) {
        float s = b2[j];
#pragma unroll
        for (int i = 0; i < 32; i++) s = fmaf(h[i], W2[i * 16 + j], s);
        x16[(size_t)n * 16 + j] = fmaxf(s, 0.f);
    }
}

// ---- CSR build (fused: both src and dst sides) ----
__global__ void deg2_kernel(const int* __restrict__ srcA, const int* __restrict__ dstA,
                            int* __restrict__ cntS, int* __restrict__ degD, int E)
{
    int i = blockIdx.x * blockDim.x + threadIdx.x;
    if (i < E) {
        atomicAdd(&cntS[srcA[i]], 1);
        atomicAdd(&degD[dstA[i]], 1);
    }
}
// wave-scan offsets: 1 cursor atomic per wave instead of per thread
__global__ void offsets2_kernel(const int* __restrict__ cntS, const int* __restrict__ degD,
                                int* __restrict__ offsS, int* __restrict__ curS,
                                int* __restrict__ offsD, int* __restrict__ curD,
                                int* __restrict__ cursS, int* __restrict__ cursD, int N)
{
    int n = blockIdx.x * blockDim.x + threadIdx.x;
    int lane = threadIdx.x & 63;
    bool valid = n < N;
    int dS = valid ? cntS[n] : 0;
    int dD = valid ? degD[n] : 0;
    int sS = dS, sD = dD;
#pragma unroll
    for (int o = 1; o < 64; o <<= 1) {
        int tS = __shfl_up(sS, o);
        int tD = __shfl_up(sD, o);
        if (lane >= o) { sS += tS; sD += tD; }
    }
    int totS = __shfl(sS, 63);
    int totD = __shfl(sD, 63);
    int baseS = 0, baseD = 0;
    if (lane == 63) {
        baseS = atomicAdd(cursS, totS);
        baseD = atomicAdd(cursD, totD);
    }
    baseS = __shfl(baseS, 63);
    baseD = __shfl(baseD, 63);
    if (valid) {
        int oS = baseS + sS - dS;
        int oD = baseD + sD - dD;
        offsS[n] = oS; curS[n] = oS;
        offsD[n] = oD; curD[n] = oD;
    }
}
// fused fill: src-sorted position p (compute row), dst-sorted position q (msg row)
__global__ void fill2_kernel(const int* __restrict__ srcA, const int* __restrict__ dstA,
                             int* __restrict__ curS, int* __restrict__ curD,
                             int* __restrict__ eid_src, int* __restrict__ srcnode,
                             int* __restrict__ p2q, int E)
{
    int e = blockIdx.x * blockDim.x + threadIdx.x;
    if (e < E) {
        int s = srcA[e];
        int p = atomicAdd(&curS[s], 1);
        eid_src[p] = e;
        srcnode[p] = s;
        int q = atomicAdd(&curD[dstA[e]], 1);
        p2q[p] = q;
    }
}

// ---- per-(node, k-slot) Y precompute: grid.y = 17 slots; slot16 = x@B ----
template <int IN>
__global__ __launch_bounds__(BS) void ynode_kernel(const float* __restrict__ x,
                                                   const float* __restrict__ W,  // [3][16][IN*8]
                                                   const float* __restrict__ B,  // [3][IN*8]
                                                   unsigned short* __restrict__ Y, int N)
{
    int n = blockIdx.x * BS + threadIdx.x;
    int k = blockIdx.y;            // 0..16, block-uniform
    bool valid = n < N;
    int nn = valid ? n : 0;
    float xv[IN];
#pragma unroll
    for (int i = 0; i < IN; i += 4)
        *(float4*)(xv + i) = *(const float4*)(x + (size_t)nn * IN + i);

    float r[24];
#pragma unroll
    for (int j = 0; j < 24; j++) r[j] = 0.f;

    if (k < 16) {
        const float* w = W + (size_t)k * (IN * 8);
#pragma unroll
        for (int a = 0; a < 3; a++) {
            const float* wa = w + (size_t)a * (16 * IN * 8);
#pragma unroll
            for (int i = 0; i < IN; i++) {
                float xi = xv[i];
#pragma unroll
                for (int o = 0; o < 8; o++)
                    r[a * 8 + o] = fmaf(xi, wa[i * 8 + o], r[a * 8 + o]);
            }
        }
    } else {
#pragma unroll
        for (int a = 0; a < 3; a++) {
            const float* ba = B + (size_t)a * (IN * 8);
#pragma unroll
            for (int i = 0; i < IN; i++) {
                float xi = xv[i];
#pragma unroll
                for (int o = 0; o < 8; o++)
                    r[a * 8 + o] = fmaf(xi, ba[i * 8 + o], r[a * 8 + o]);
            }
        }
    }
    if (valid) st24bf(Y + (size_t)n * 408 + k * 24, r);
}

// ---- edge trunk only: er_s[p] = sigmoid(relu(eattr[e] @ W1 + b1) @ W2 + b2) ----
__global__ __launch_bounds__(BS) void er_kernel(
    const int* __restrict__ eid_src, const float* __restrict__ eattr,
    const float* __restrict__ eW1, const float* __restrict__ eb1,
    const float* __restrict__ eW2, const float* __restrict__ eb2,
    unsigned short* __restrict__ er_s, int E)
{
    int p = blockIdx.x * BS + threadIdx.x;
    if (p >= E) return;
    int e = eid_src[p];
    float ea[16];
#pragma unroll
    for (int i = 0; i < 16; i += 4)
        *(float4*)(ea + i) = *(const float4*)(eattr + (size_t)e * 16 + i);
    float h[32];
#pragma unroll
    for (int j = 0; j < 32; j++) {
        float s = eb1[j];
#pragma unroll
        for (int i = 0; i < 16; i++) s = fmaf(ea[i], eW1[i * 32 + j], s);
        h[j] = fmaxf(s, 0.f);
    }
    float er[16];
#pragma unroll
    for (int j = 0; j < 16; j++) {
        float s = eb2[j];
#pragma unroll
        for (int i = 0; i < 32; i++) s = fmaf(h[i], eW2[i * 16 + j], s);
        er[j] = 1.f / (1.f + __expf(-s));
    }
    unsigned w[8];
#pragma unroll
    for (int j = 0; j < 8; j++)
        w[j] = (unsigned)f2bf(er[2 * j]) | ((unsigned)f2bf(er[2 * j + 1]) << 16);
    uint4* q = (uint4*)(er_s + (size_t)p * 16);
    q[0] = make_uint4(w[0], w[1], w[2], w[3]);
    q[1] = make_uint4(w[4], w[5], w[6], w[7]);
}

// ---- per-(edge, 8-col part) msg: compute in src order (Y locality), write at dst slot ----
__global__ __launch_bounds__(BS) void msg_kernel(
    const int* __restrict__ srcnode,
    const int* __restrict__ p2q,
    const unsigned short* __restrict__ er_s,   // [E][16] bf16, src-sorted
    const unsigned short* __restrict__ Y,
    float* __restrict__ msg, int E)
{
    int tid = blockIdx.x * BS + threadIdx.x;
    int p = tid / 3;
    int j = tid - p * 3;
    if (p >= E) return;

    float er[16];
    {
        const uint4* eu = (const uint4*)(er_s + (size_t)p * 16);
        unpack8(eu[0], er);
        unpack8(eu[1], er + 8);
    }

    int s = srcnode[p];
    const uint4* yu = (const uint4*)(Y + (size_t)s * 408) + j;

    float acc[8];
    unpack8(yu[48], acc);         // bias slot (orig index 48+j)
#pragma unroll
    for (int k = 0; k < 16; k++) {
        float t[8];
        unpack8(yu[k * 3], t);
        float ek = er[k];
#pragma unroll
        for (int q = 0; q < 8; q++) acc[q] = fmaf(ek, t[q], acc[q]);
    }
    int q = p2q[p];
    float* m = msg + (size_t)q * 24 + j * 8;
    *(float4*)(m)     = make_float4(acc[0], acc[1], acc[2], acc[3]);
    *(float4*)(m + 4) = make_float4(acc[4], acc[5], acc[6], acc[7]);
}

// ---- wave-per-node gather: 8-row x 96B coalesced tiles, shfl-reduce, root+relu ----
template <int IN>
__global__ __launch_bounds__(BS) void gather_kernel(
    const float* __restrict__ x,
    const float* __restrict__ msg,       // [E][24], dst-sorted
    const int* __restrict__ offs,
    const int* __restrict__ degi,
    const float* __restrict__ rootW,     // [3][IN][8]
    const float* __restrict__ bias,      // [3][8]
    float* __restrict__ out, int N)
{
    int n = (blockIdx.x * BS + threadIdx.x) >> 6;   // one wave per node
    if (n >= N) return;
    int lane = threadIdx.x & 63;
    int c = lane & 7;     // float4-chunk 0..7 (0..5 active)
    int r = lane >> 3;    // row within 8-row tile

    int off = offs[n];
    int d = degi[n];

    float s0 = 0.f, s1 = 0.f, s2 = 0.f, s3 = 0.f;
    float m0 = -3.402823466e38f, m1 = m0, m2 = m0, m3 = m0;
    if (c < 6) {
        const float* base = msg + (size_t)off * 24 + c * 4;
        for (int j = r; j < d; j += 8) {
            float4 v = *(const float4*)(base + (size_t)j * 24);
            s0 += v.x; s1 += v.y; s2 += v.z; s3 += v.w;
            m0 = fmaxf(m0, v.x); m1 = fmaxf(m1, v.y);
            m2 = fmaxf(m2, v.z); m3 = fmaxf(m3, v.w);
        }
    }
    // reduce across rows r (lane strides of 8): masks 8,16,32
#pragma unroll
    for (int mask = 8; mask < 64; mask <<= 1) {
        s0 += __shfl_xor(s0, mask); s1 += __shfl_xor(s1, mask);
        s2 += __shfl_xor(s2, mask); s3 += __shfl_xor(s3, mask);
        m0 = fmaxf(m0, __shfl_xor(m0, mask)); m1 = fmaxf(m1, __shfl_xor(m1, mask));
        m2 = fmaxf(m2, __shfl_xor(m2, mask)); m3 = fmaxf(m3, __shfl_xor(m3, mask));
    }
    if (r != 0 || c >= 6) return;

    // lane c (0..5) finalizes output cols c*4..c*4+3; aggregator a = c>>1
    int a = c >> 1;
    float inv = 1.f / fmaxf((float)d, 1.f);
    float sv[4] = {s0, s1, s2, s3};
    float mv[4] = {m0, m1, m2, m3};
    float rr[4];
#pragma unroll
    for (int q = 0; q < 4; q++) {
        float agg = (a == 0) ? sv[q] * inv
                  : (a == 1) ? ((d > 0) ? mv[q] : 0.f)
                  : sv[q];
        int o = (c & 1) * 4 + q;       // output col within the 8-wide aggregator block
        float s = bias[a * 8 + o];
#pragma unroll
        for (int i = 0; i < IN; i++)
            s = fmaf(x[(size_t)n * IN + i], rootW[(a * IN + i) * 8 + o], s);
        rr[q] = fmaxf(s + agg, 0.f);
    }
    *(float4*)(out + (size_t)n * 24 + c * 4) = make_float4(rr[0], rr[1], rr[2], rr[3]);
}

// ---- output head ----
__global__ void head_kernel(const float* __restrict__ x, const float* __restrict__ W,
                            const float* __restrict__ b, float* __restrict__ out, int N)
{
    int n = blockIdx.x * blockDim.x + threadIdx.x;
    if (n >= N) return;
    float l0 = b[0], l1 = b[1];
#pragma unroll
    for (int i = 0; i < 24; i++) {
        float xi = x[(size_t)n * 24 + i];
        l0 = fmaf(xi, W[i * 2 + 0], l0);
        l1 = fmaf(xi, W[i * 2 + 1], l1);
    }
    out[2 * (size_t)n + 0] = l0;
    out[2 * (size_t)n + 1] = l1;
    float m = fmaxf(l0, l1);
    float e0 = __expf(l0 - m), e1 = __expf(l1 - m);
    float s = e0 + e1;
    out[2 * (size_t)N + 2 * (size_t)n + 0] = e0 / s;
    out[2 * (size_t)N + 2 * (size_t)n + 1] = e1 / s;
}

extern "C" void kernel_launch(void* const* d_in, const int* in_sizes, int n_in,
                              void* d_out, int out_size, void* d_ws, size_t ws_size,
                              hipStream_t stream)
{
    const float* x_feat = (const float*)d_in[0];
    const int*   eidx   = (const int*)d_in[1];
    const float* eattr  = (const float*)d_in[2];
    const float* lpW = (const float*)d_in[3];
    const float* lpb = (const float*)d_in[4];
    const float* tW  = (const float*)d_in[5];
    const float* tb  = (const float*)d_in[6];
    const float* eW1 = (const float*)d_in[7];
    const float* eb1 = (const float*)d_in[8];
    const float* eW2 = (const float*)d_in[9];
    const float* eb2 = (const float*)d_in[10];
    const float* c1W = (const float*)d_in[11];
    const float* c1B = (const float*)d_in[12];
    const float* c1R = (const float*)d_in[13];
    const float* c1b = (const float*)d_in[14];
    const float* c2W = (const float*)d_in[15];
    const float* c2B = (const float*)d_in[16];
    const float* c2R = (const float*)d_in[17];
    const float* c2b = (const float*)d_in[18];
    const float* oW  = (const float*)d_in[19];
    const float* ob  = (const float*)d_in[20];

    int N = in_sizes[0] / 24;
    int E = in_sizes[1] / 2;
    const int* srcA = eidx;
    const int* dstA = eidx + E;

    char* wsb = (char*)d_ws;
    size_t off = 0;
    auto alloc = [&](size_t bytes) {
        off = (off + 255) & ~(size_t)255;
        void* p = wsb + off;
        off += bytes;
        return p;
    };
    unsigned short* Y    = (unsigned short*)alloc((size_t)N * 408 * 2);
    float* msg  = (float*)alloc((size_t)E * 24 * 4);
    unsigned short* er_s = (unsigned short*)alloc((size_t)E * 16 * 2);
    float* x16  = (float*)alloc((size_t)N * 16 * 4);
    float* x24a = (float*)alloc((size_t)N * 24 * 4);
    float* x24b = (float*)alloc((size_t)N * 24 * 4);
    int* ibase  = (int*)alloc(((size_t)2 * N + 2) * 4);  // cntS | degD | cursS | cursD (zeroed)
    int* cntS = ibase;
    int* degD = ibase + N;
    int* cursS = ibase + 2 * N;
    int* cursD = ibase + 2 * N + 1;
    int* offsD = (int*)alloc((size_t)N * 4);
    int* curD  = (int*)alloc((size_t)N * 4);
    int* offsS = (int*)alloc((size_t)N * 4);
    int* curS  = (int*)alloc((size_t)N * 4);
    int* eid_src = (int*)alloc((size_t)E * 4);
    int* srcnode = (int*)alloc((size_t)E * 4);
    int* p2q     = (int*)alloc((size_t)E * 4);

    dim3 blk(BS);
    int nb_nodes = (N + BS - 1) / BS;
    int nb_edges = (E + BS - 1) / BS;
    int nb_msg   = (3 * E + BS - 1) / BS;
    int nb_gath  = ((size_t)N * 64 + BS - 1) / BS;   // one wave per node
    dim3 ygrid(nb_nodes, 17);

    hipMemsetAsync(ibase, 0, (2 * (size_t)N + 2) * 4, stream);

    prep_kernel<<<nb_nodes, blk, 0, stream>>>(x_feat, lpW, lpb, tW, tb, x16, N);

    deg2_kernel<<<nb_edges, blk, 0, stream>>>(srcA, dstA, cntS, degD, E);
    offsets2_kernel<<<nb_nodes, blk, 0, stream>>>(cntS, degD, offsS, curS, offsD, curD,
                                                  cursS, cursD, N);
    fill2_kernel<<<nb_edges, blk, 0, stream>>>(srcA, dstA, curS, curD,
                                               eid_src, srcnode, p2q, E);

    er_kernel<<<nb_edges, blk, 0, stream>>>(eid_src, eattr, eW1, eb1, eW2, eb2, er_s, E);

    // ---- conv1 ----
    ynode_kernel<16><<<ygrid, blk, 0, stream>>>(x16, c1W, c1B, Y, N);
    msg_kernel<<<nb_msg, blk, 0, stream>>>(srcnode, p2q, er_s, Y, msg, E);
    gather_kernel<16><<<nb_gath, blk, 0, stream>>>(x16, msg, offsD, degD, c1R, c1b, x24a, N);

    // ---- conv2 ----
    ynode_kernel<24><<<ygrid, blk, 0, stream>>>(x24a, c2W, c2B, Y, N);
    msg_kernel<<<nb_msg, blk, 0, stream>>>(srcnode, p2q, er_s, Y, msg, E);
    gather_kernel<24><<<nb_gath, blk, 0, stream>>>(x24a, msg, offsD, degD, c2R, c2b, x24b, N);

    head_kernel<<<nb_nodes, blk, 0, stream>>>(x24b, oW, ob, (float*)d_out, N);
}

// Round 9
// 338.678 us; speedup vs baseline: 4.1165x; 1.2455x over previous
//
#include <hip/hip_runtime.h>

#define BS 256

// ---------------- bf16 helpers ----------------
__device__ __forceinline__ unsigned short f2bf(float f) {
    unsigned x = __float_as_uint(f);
    return (unsigned short)((x + 0x7fffu + ((x >> 16) & 1u)) >> 16);
}
__device__ __forceinline__ void unpack8(uint4 v, float* d) {
    d[0] = __uint_as_float(v.x << 16); d[1] = __uint_as_float(v.x & 0xFFFF0000u);
    d[2] = __uint_as_float(v.y << 16); d[3] = __uint_as_float(v.y & 0xFFFF0000u);
    d[4] = __uint_as_float(v.z << 16); d[5] = __uint_as_float(v.z & 0xFFFF0000u);
    d[6] = __uint_as_float(v.w << 16); d[7] = __uint_as_float(v.w & 0xFFFF0000u);
}
// store 24 floats as 24 bf16 (48 B = 3x uint4)
__device__ __forceinline__ void st24bf(unsigned short* p, const float* r) {
    unsigned w[12];
#pragma unroll
    for (int j = 0; j < 12; j++)
        w[j] = (unsigned)f2bf(r[2 * j]) | ((unsigned)f2bf(r[2 * j + 1]) << 16);
    uint4* q = (uint4*)p;
    q[0] = make_uint4(w[0], w[1], w[2], w[3]);
    q[1] = make_uint4(w[4], w[5], w[6], w[7]);
    q[2] = make_uint4(w[8], w[9], w[10], w[11]);
}

// ---- node prep: x16 = relu(relu(x_feat @ lpW + lpb) @ tW + tb) ----
__global__ void prep_kernel(const float* __restrict__ xf,
                            const float* __restrict__ W1, const float* __restrict__ b1,
                            const float* __restrict__ W2, const float* __restrict__ b2,
                            float* __restrict__ x16, int N)
{
    int n = blockIdx.x * blockDim.x + threadIdx.x;
    bool valid = n < N;
    int nn = valid ? n : 0;
    float a[24];
#pragma unroll
    for (int i = 0; i < 24; i += 4)
        *(float4*)(a + i) = *(const float4*)(xf + (size_t)nn * 24 + i);
    float h[32];
#pragma unroll
    for (int j = 0; j < 32; j++) {
        float s = b1[j];
#pragma unroll
        for (int i = 0; i < 24; i++) s = fmaf(a[i], W1[i * 32 + j], s);
        h[j] = fmaxf(s, 0.f);
    }
    if (!valid) return;
#pragma unroll
    for (int j = 0; j < 16; j++) {
        float s = b2[j];
#pragma unroll
        for (int i = 0; i < 32; i++) s = fmaf(h[i], W2[i * 16 + j], s);
        x16[(size_t)n * 16 + j] = fmaxf(s, 0.f);
    }
}

// ---- CSR build (fused: both src and dst sides) ----
__global__ void deg2_kernel(const int* __restrict__ srcA, const int* __restrict__ dstA,
                            int* __restrict__ cntS, int* __restrict__ degD, int E)
{
    int i = blockIdx.x * blockDim.x + threadIdx.x;
    if (i < E) {
        atomicAdd(&cntS[srcA[i]], 1);
        atomicAdd(&degD[dstA[i]], 1);
    }
}
// wave-scan offsets: 1 cursor atomic per wave instead of per thread
__global__ void offsets2_kernel(const int* __restrict__ cntS, const int* __restrict__ degD,
                                int* __restrict__ offsS, int* __restrict__ curS,
                                int* __restrict__ offsD, int* __restrict__ curD,
                                int* __restrict__ cursS, int* __restrict__ cursD, int N)
{
    int n = blockIdx.x * blockDim.x + threadIdx.x;
    int lane = threadIdx.x & 63;
    bool valid = n < N;
    int dS = valid ? cntS[n] : 0;
    int dD = valid ? degD[n] : 0;
    int sS = dS, sD = dD;
#pragma unroll
    for (int o = 1; o < 64; o <<= 1) {
        int tS = __shfl_up(sS, o);
        int tD = __shfl_up(sD, o);
        if (lane >= o) { sS += tS; sD += tD; }
    }
    int totS = __shfl(sS, 63);
    int totD = __shfl(sD, 63);
    int baseS = 0, baseD = 0;
    if (lane == 63) {
        baseS = atomicAdd(cursS, totS);
        baseD = atomicAdd(cursD, totD);
    }
    baseS = __shfl(baseS, 63);
    baseD = __shfl(baseD, 63);
    if (valid) {
        int oS = baseS + sS - dS;
        int oD = baseD + sD - dD;
        offsS[n] = oS; curS[n] = oS;
        offsD[n] = oD; curD[n] = oD;
    }
}
// fused fill: src-sorted position p (compute row), dst-sorted position q (msg row)
__global__ void fill2_kernel(const int* __restrict__ srcA, const int* __restrict__ dstA,
                             int* __restrict__ curS, int* __restrict__ curD,
                             int* __restrict__ eid_src, int* __restrict__ srcnode,
                             int* __restrict__ p2q, int E)
{
    int e = blockIdx.x * blockDim.x + threadIdx.x;
    if (e < E) {
        int s = srcA[e];
        int p = atomicAdd(&curS[s], 1);
        eid_src[p] = e;
        srcnode[p] = s;
        int q = atomicAdd(&curD[dstA[e]], 1);
        p2q[p] = q;
    }
}

// ---- per-(node, k-slot) Y precompute: grid.y = 18 slots ----
// k in [0,16): Y[n,k,:] = x @ W[:,k,:];  k==16: Y bias slot = x @ B;
// k==17: root[n,:] = x @ rootW + rootB (fp32).
template <int IN>
__global__ __launch_bounds__(BS) void ynode_kernel(const float* __restrict__ x,
                                                   const float* __restrict__ W,   // [3][16][IN*8]
                                                   const float* __restrict__ B,   // [3][IN*8]
                                                   const float* __restrict__ RW,  // [3][IN][8]
                                                   const float* __restrict__ RB,  // [3][8]
                                                   unsigned short* __restrict__ Y,
                                                   float* __restrict__ root, int N)
{
    int n = blockIdx.x * BS + threadIdx.x;
    int k = blockIdx.y;            // 0..17, block-uniform
    bool valid = n < N;
    int nn = valid ? n : 0;
    float xv[IN];
#pragma unroll
    for (int i = 0; i < IN; i += 4)
        *(float4*)(xv + i) = *(const float4*)(x + (size_t)nn * IN + i);

    float r[24];
#pragma unroll
    for (int j = 0; j < 24; j++) r[j] = 0.f;

    if (k < 16) {
        const float* w = W + (size_t)k * (IN * 8);
#pragma unroll
        for (int a = 0; a < 3; a++) {
            const float* wa = w + (size_t)a * (16 * IN * 8);
#pragma unroll
            for (int i = 0; i < IN; i++) {
                float xi = xv[i];
#pragma unroll
                for (int o = 0; o < 8; o++)
                    r[a * 8 + o] = fmaf(xi, wa[i * 8 + o], r[a * 8 + o]);
            }
        }
        if (valid) st24bf(Y + (size_t)n * 408 + k * 24, r);
    } else if (k == 16) {
#pragma unroll
        for (int a = 0; a < 3; a++) {
            const float* ba = B + (size_t)a * (IN * 8);
#pragma unroll
            for (int i = 0; i < IN; i++) {
                float xi = xv[i];
#pragma unroll
                for (int o = 0; o < 8; o++)
                    r[a * 8 + o] = fmaf(xi, ba[i * 8 + o], r[a * 8 + o]);
            }
        }
        if (valid) st24bf(Y + (size_t)n * 408 + 16 * 24, r);
    } else {  // k == 17: root transform, fp32
#pragma unroll
        for (int j = 0; j < 24; j++) r[j] = RB[j];
#pragma unroll
        for (int a = 0; a < 3; a++) {
            const float* wa = RW + (size_t)a * (IN * 8);
#pragma unroll
            for (int i = 0; i < IN; i++) {
                float xi = xv[i];
#pragma unroll
                for (int o = 0; o < 8; o++)
                    r[a * 8 + o] = fmaf(xi, wa[i * 8 + o], r[a * 8 + o]);
            }
        }
        if (valid) {
            float* pr = root + (size_t)n * 24;
#pragma unroll
            for (int j = 0; j < 24; j += 4)
                *(float4*)(pr + j) = make_float4(r[j], r[j + 1], r[j + 2], r[j + 3]);
        }
    }
}

// ---- edge trunk only: er_s[p] = sigmoid(relu(eattr[e] @ W1 + b1) @ W2 + b2) ----
__global__ __launch_bounds__(BS) void er_kernel(
    const int* __restrict__ eid_src, const float* __restrict__ eattr,
    const float* __restrict__ eW1, const float* __restrict__ eb1,
    const float* __restrict__ eW2, const float* __restrict__ eb2,
    unsigned short* __restrict__ er_s, int E)
{
    int p = blockIdx.x * BS + threadIdx.x;
    if (p >= E) return;
    int e = eid_src[p];
    float ea[16];
#pragma unroll
    for (int i = 0; i < 16; i += 4)
        *(float4*)(ea + i) = *(const float4*)(eattr + (size_t)e * 16 + i);
    float h[32];
#pragma unroll
    for (int j = 0; j < 32; j++) {
        float s = eb1[j];
#pragma unroll
        for (int i = 0; i < 16; i++) s = fmaf(ea[i], eW1[i * 32 + j], s);
        h[j] = fmaxf(s, 0.f);
    }
    float er[16];
#pragma unroll
    for (int j = 0; j < 16; j++) {
        float s = eb2[j];
#pragma unroll
        for (int i = 0; i < 32; i++) s = fmaf(h[i], eW2[i * 16 + j], s);
        er[j] = 1.f / (1.f + __expf(-s));
    }
    unsigned w[8];
#pragma unroll
    for (int j = 0; j < 8; j++)
        w[j] = (unsigned)f2bf(er[2 * j]) | ((unsigned)f2bf(er[2 * j + 1]) << 16);
    uint4* q = (uint4*)(er_s + (size_t)p * 16);
    q[0] = make_uint4(w[0], w[1], w[2], w[3]);
    q[1] = make_uint4(w[4], w[5], w[6], w[7]);
}

// ---- per-(edge, 8-col part) msg: compute in src order (Y locality), write at dst slot ----
__global__ __launch_bounds__(BS) void msg_kernel(
    const int* __restrict__ srcnode,
    const int* __restrict__ p2q,
    const unsigned short* __restrict__ er_s,   // [E][16] bf16, src-sorted
    const unsigned short* __restrict__ Y,
    float* __restrict__ msg, int E)
{
    int tid = blockIdx.x * BS + threadIdx.x;
    int p = tid / 3;
    int j = tid - p * 3;
    if (p >= E) return;

    float er[16];
    {
        const uint4* eu = (const uint4*)(er_s + (size_t)p * 16);
        unpack8(eu[0], er);
        unpack8(eu[1], er + 8);
    }

    int s = srcnode[p];
    const uint4* yu = (const uint4*)(Y + (size_t)s * 408) + j;

    float acc[8];
    unpack8(yu[48], acc);         // bias slot (orig index 48+j)
#pragma unroll
    for (int k = 0; k < 16; k++) {
        float t[8];
        unpack8(yu[k * 3], t);
        float ek = er[k];
#pragma unroll
        for (int q = 0; q < 8; q++) acc[q] = fmaf(ek, t[q], acc[q]);
    }
    int q = p2q[p];
    float* m = msg + (size_t)q * 24 + j * 8;
    *(float4*)(m)     = make_float4(acc[0], acc[1], acc[2], acc[3]);
    *(float4*)(m + 4) = make_float4(acc[4], acc[5], acc[6], acc[7]);
}

// ---- wave-per-node gather: coalesced tiles, shfl-reduce, add precomputed root ----
__global__ __launch_bounds__(BS) void gather_kernel(
    const float* __restrict__ msg,       // [E][24], dst-sorted
    const int* __restrict__ offs,
    const int* __restrict__ degi,
    const float* __restrict__ root,      // [N][24] fp32
    float* __restrict__ out, int N)
{
    int n = (blockIdx.x * BS + threadIdx.x) >> 6;   // one wave per node
    if (n >= N) return;
    int lane = threadIdx.x & 63;
    int c = lane & 7;     // float4-chunk 0..7 (0..5 active)
    int r = lane >> 3;    // row within 8-row tile

    int off = offs[n];
    int d = degi[n];

    float s0 = 0.f, s1 = 0.f, s2 = 0.f, s3 = 0.f;
    float m0 = -3.402823466e38f, m1 = m0, m2 = m0, m3 = m0;
    if (c < 6) {
        const float* base = msg + (size_t)off * 24 + c * 4;
        for (int j = r; j < d; j += 8) {
            float4 v = *(const float4*)(base + (size_t)j * 24);
            s0 += v.x; s1 += v.y; s2 += v.z; s3 += v.w;
            m0 = fmaxf(m0, v.x); m1 = fmaxf(m1, v.y);
            m2 = fmaxf(m2, v.z); m3 = fmaxf(m3, v.w);
        }
    }
    // reduce across rows r (lane strides of 8): masks 8,16,32
#pragma unroll
    for (int mask = 8; mask < 64; mask <<= 1) {
        s0 += __shfl_xor(s0, mask); s1 += __shfl_xor(s1, mask);
        s2 += __shfl_xor(s2, mask); s3 += __shfl_xor(s3, mask);
        m0 = fmaxf(m0, __shfl_xor(m0, mask)); m1 = fmaxf(m1, __shfl_xor(m1, mask));
        m2 = fmaxf(m2, __shfl_xor(m2, mask)); m3 = fmaxf(m3, __shfl_xor(m3, mask));
    }
    if (r != 0 || c >= 6) return;

    // lane c (0..5) finalizes output cols c*4..c*4+3; aggregator a = c>>1
    int a = c >> 1;
    float inv = 1.f / fmaxf((float)d, 1.f);
    float4 rv = *(const float4*)(root + (size_t)n * 24 + c * 4);
    float sv[4] = {s0, s1, s2, s3};
    float mv[4] = {m0, m1, m2, m3};
    float rb[4] = {rv.x, rv.y, rv.z, rv.w};
    float rr[4];
#pragma unroll
    for (int q = 0; q < 4; q++) {
        float agg = (a == 0) ? sv[q] * inv
                  : (a == 1) ? ((d > 0) ? mv[q] : 0.f)
                  : sv[q];
        rr[q] = fmaxf(rb[q] + agg, 0.f);
    }
    *(float4*)(out + (size_t)n * 24 + c * 4) = make_float4(rr[0], rr[1], rr[2], rr[3]);
}

// ---- output head ----
__global__ void head_kernel(const float* __restrict__ x, const float* __restrict__ W,
                            const float* __restrict__ b, float* __restrict__ out, int N)
{
    int n = blockIdx.x * blockDim.x + threadIdx.x;
    if (n >= N) return;
    float l0 = b[0], l1 = b[1];
#pragma unroll
    for (int i = 0; i < 24; i++) {
        float xi = x[(size_t)n * 24 + i];
        l0 = fmaf(xi, W[i * 2 + 0], l0);
        l1 = fmaf(xi, W[i * 2 + 1], l1);
    }
    out[2 * (size_t)n + 0] = l0;
    out[2 * (size_t)n + 1] = l1;
    float m = fmaxf(l0, l1);
    float e0 = __expf(l0 - m), e1 = __expf(l1 - m);
    float s = e0 + e1;
    out[2 * (size_t)N + 2 * (size_t)n + 0] = e0 / s;
    out[2 * (size_t)N + 2 * (size_t)n + 1] = e1 / s;
}

extern "C" void kernel_launch(void* const* d_in, const int* in_sizes, int n_in,
                              void* d_out, int out_size, void* d_ws, size_t ws_size,
                              hipStream_t stream)
{
    const float* x_feat = (const float*)d_in[0];
    const int*   eidx   = (const int*)d_in[1];
    const float* eattr  = (const float*)d_in[2];
    const float* lpW = (const float*)d_in[3];
    const float* lpb = (const float*)d_in[4];
    const float* tW  = (const float*)d_in[5];
    const float* tb  = (const float*)d_in[6];
    const float* eW1 = (const float*)d_in[7];
    const float* eb1 = (const float*)d_in[8];
    const float* eW2 = (const float*)d_in[9];
    const float* eb2 = (const float*)d_in[10];
    const float* c1W = (const float*)d_in[11];
    const float* c1B = (const float*)d_in[12];
    const float* c1R = (const float*)d_in[13];
    const float* c1b = (const float*)d_in[14];
    const float* c2W = (const float*)d_in[15];
    const float* c2B = (const float*)d_in[16];
    const float* c2R = (const float*)d_in[17];
    const float* c2b = (const float*)d_in[18];
    const float* oW  = (const float*)d_in[19];
    const float* ob  = (const float*)d_in[20];

    int N = in_sizes[0] / 24;
    int E = in_sizes[1] / 2;
    const int* srcA = eidx;
    const int* dstA = eidx + E;

    char* wsb = (char*)d_ws;
    size_t off = 0;
    auto alloc = [&](size_t bytes) {
        off = (off + 255) & ~(size_t)255;
        void* p = wsb + off;
        off += bytes;
        return p;
    };
    unsigned short* Y    = (unsigned short*)alloc((size_t)N * 408 * 2);
    float* msg  = (float*)alloc((size_t)E * 24 * 4);
    unsigned short* er_s = (unsigned short*)alloc((size_t)E * 16 * 2);
    float* root = (float*)alloc((size_t)N * 24 * 4);
    float* x16  = (float*)alloc((size_t)N * 16 * 4);
    float* x24a = (float*)alloc((size_t)N * 24 * 4);
    float* x24b = (float*)alloc((size_t)N * 24 * 4);
    int* ibase  = (int*)alloc(((size_t)2 * N + 2) * 4);  // cntS | degD | cursS | cursD (zeroed)
    int* cntS = ibase;
    int* degD = ibase + N;
    int* cursS = ibase + 2 * N;
    int* cursD = ibase + 2 * N + 1;
    int* offsD = (int*)alloc((size_t)N * 4);
    int* curD  = (int*)alloc((size_t)N * 4);
    int* offsS = (int*)alloc((size_t)N * 4);
    int* curS  = (int*)alloc((size_t)N * 4);
    int* eid_src = (int*)alloc((size_t)E * 4);
    int* srcnode = (int*)alloc((size_t)E * 4);
    int* p2q     = (int*)alloc((size_t)E * 4);

    dim3 blk(BS);
    int nb_nodes = (N + BS - 1) / BS;
    int nb_edges = (E + BS - 1) / BS;
    int nb_msg   = (3 * E + BS - 1) / BS;
    int nb_gath  = ((size_t)N * 64 + BS - 1) / BS;   // one wave per node
    dim3 ygrid(nb_nodes, 18);

    hipMemsetAsync(ibase, 0, (2 * (size_t)N + 2) * 4, stream);

    prep_kernel<<<nb_nodes, blk, 0, stream>>>(x_feat, lpW, lpb, tW, tb, x16, N);

    deg2_kernel<<<nb_edges, blk, 0, stream>>>(srcA, dstA, cntS, degD, E);
    offsets2_kernel<<<nb_nodes, blk, 0, stream>>>(cntS, degD, offsS, curS, offsD, curD,
                                                  cursS, cursD, N);
    fill2_kernel<<<nb_edges, blk, 0, stream>>>(srcA, dstA, curS, curD,
                                               eid_src, srcnode, p2q, E);

    er_kernel<<<nb_edges, blk, 0, stream>>>(eid_src, eattr, eW1, eb1, eW2, eb2, er_s, E);

    // ---- conv1 ----
    ynode_kernel<16><<<ygrid, blk, 0, stream>>>(x16, c1W, c1B, c1R, c1b, Y, root, N);
    msg_kernel<<<nb_msg, blk, 0, stream>>>(srcnode, p2q, er_s, Y, msg, E);
    gather_kernel<<<nb_gath, blk, 0, stream>>>(msg, offsD, degD, root, x24a, N);

    // ---- conv2 ----
    ynode_kernel<24><<<ygrid, blk, 0, stream>>>(x24a, c2W, c2B, c2R, c2b, Y, root, N);
    msg_kernel<<<nb_msg, blk, 0, stream>>>(srcnode, p2q, er_s, Y, msg, E);
    gather_kernel<<<nb_gath, blk, 0, stream>>>(msg, offsD, degD, root, x24b, N);

    head_kernel<<<nb_nodes, blk, 0, stream>>>(x24b, oW, ob, (float*)d_out, N);
}

// Round 10
// 295.762 us; speedup vs baseline: 4.7139x; 1.1451x over previous
//
#include <hip/hip_runtime.h>

#define BS 256

// ---------------- bf16 helpers ----------------
__device__ __forceinline__ unsigned short f2bf(float f) {
    unsigned x = __float_as_uint(f);
    return (unsigned short)((x + 0x7fffu + ((x >> 16) & 1u)) >> 16);
}
__device__ __forceinline__ void unpack8(uint4 v, float* d) {
    d[0] = __uint_as_float(v.x << 16); d[1] = __uint_as_float(v.x & 0xFFFF0000u);
    d[2] = __uint_as_float(v.y << 16); d[3] = __uint_as_float(v.y & 0xFFFF0000u);
    d[4] = __uint_as_float(v.z << 16); d[5] = __uint_as_float(v.z & 0xFFFF0000u);
    d[6] = __uint_as_float(v.w << 16); d[7] = __uint_as_float(v.w & 0xFFFF0000u);
}
__device__ __forceinline__ uint4 pack8bf(const float* r) {
    unsigned w[4];
#pragma unroll
    for (int j = 0; j < 4; j++)
        w[j] = (unsigned)f2bf(r[2 * j]) | ((unsigned)f2bf(r[2 * j + 1]) << 16);
    return make_uint4(w[0], w[1], w[2], w[3]);
}
// store 24 floats as 24 bf16 (48 B = 3x uint4)
__device__ __forceinline__ void st24bf(unsigned short* p, const float* r) {
    uint4* q = (uint4*)p;
    q[0] = pack8bf(r);
    q[1] = pack8bf(r + 8);
    q[2] = pack8bf(r + 16);
}

// ---- node prep: x16 = relu(relu(x_feat @ lpW + lpb) @ tW + tb) ----
__global__ void prep_kernel(const float* __restrict__ xf,
                            const float* __restrict__ W1, const float* __restrict__ b1,
                            const float* __restrict__ W2, const float* __restrict__ b2,
                            float* __restrict__ x16, int N)
{
    int n = blockIdx.x * blockDim.x + threadIdx.x;
    bool valid = n < N;
    int nn = valid ? n : 0;
    float a[24];
#pragma unroll
    for (int i = 0; i < 24; i += 4)
        *(float4*)(a + i) = *(const float4*)(xf + (size_t)nn * 24 + i);
    float h[32];
#pragma unroll
    for (int j = 0; j < 32; j++) {
        float s = b1[j];
#pragma unroll
        for (int i = 0; i < 24; i++) s = fmaf(a[i], W1[i * 32 + j], s);
        h[j] = fmaxf(s, 0.f);
    }
    if (!valid) return;
#pragma unroll
    for (int j = 0; j < 16; j++) {
        float s = b2[j];
#pragma unroll
        for (int i = 0; i < 32; i++) s = fmaf(h[i], W2[i * 16 + j], s);
        x16[(size_t)n * 16 + j] = fmaxf(s, 0.f);
    }
}

// ---- counting pass: histogram both sides, store occurrence index per edge ----
__global__ void degjj_kernel(const int* __restrict__ srcA, const int* __restrict__ dstA,
                             int* __restrict__ cntS, int* __restrict__ cntD,
                             int* __restrict__ jS, int* __restrict__ jD, int E)
{
    int e = blockIdx.x * blockDim.x + threadIdx.x;
    if (e < E) {
        jS[e] = atomicAdd(&cntS[srcA[e]], 1);
        jD[e] = atomicAdd(&cntD[dstA[e]], 1);
    }
}
// wave-scan offsets: 1 cursor atomic per wave
__global__ void offsets2_kernel(const int* __restrict__ cntS, const int* __restrict__ cntD,
                                int* __restrict__ offsS, int* __restrict__ offsD,
                                int* __restrict__ cursS, int* __restrict__ cursD, int N)
{
    int n = blockIdx.x * blockDim.x + threadIdx.x;
    int lane = threadIdx.x & 63;
    bool valid = n < N;
    int dS = valid ? cntS[n] : 0;
    int dD = valid ? cntD[n] : 0;
    int sS = dS, sD = dD;
#pragma unroll
    for (int o = 1; o < 64; o <<= 1) {
        int tS = __shfl_up(sS, o);
        int tD = __shfl_up(sD, o);
        if (lane >= o) { sS += tS; sD += tD; }
    }
    int totS = __shfl(sS, 63);
    int totD = __shfl(sD, 63);
    int baseS = 0, baseD = 0;
    if (lane == 63) {
        baseS = atomicAdd(cursS, totS);
        baseD = atomicAdd(cursD, totD);
    }
    baseS = __shfl(baseS, 63);
    baseD = __shfl(baseD, 63);
    if (valid) {
        offsS[n] = baseS + sS - dS;
        offsD[n] = baseD + sD - dD;
    }
}

// ---- fused fill + edge trunk: coalesced eattr, no atomics ----
// p = offsS[s]+jS[e] (src-sorted row), q = offsD[d]+jD[e] (dst-sorted msg row)
__global__ __launch_bounds__(BS) void er_fill_kernel(
    const int* __restrict__ srcA, const int* __restrict__ dstA,
    const int* __restrict__ jS, const int* __restrict__ jD,
    const int* __restrict__ offsS, const int* __restrict__ offsD,
    const float* __restrict__ eattr,
    const float* __restrict__ eW1, const float* __restrict__ eb1,
    const float* __restrict__ eW2, const float* __restrict__ eb2,
    uint2* __restrict__ spq, unsigned short* __restrict__ er_s, int E)
{
    int e = blockIdx.x * BS + threadIdx.x;
    if (e >= E) return;
    int s = srcA[e], d = dstA[e];
    int p = offsS[s] + jS[e];
    int q = offsD[d] + jD[e];
    spq[p] = make_uint2((unsigned)s, (unsigned)q);

    float ea[16];
#pragma unroll
    for (int i = 0; i < 16; i += 4)
        *(float4*)(ea + i) = *(const float4*)(eattr + (size_t)e * 16 + i);
    float h[32];
#pragma unroll
    for (int j = 0; j < 32; j++) {
        float t = eb1[j];
#pragma unroll
        for (int i = 0; i < 16; i++) t = fmaf(ea[i], eW1[i * 32 + j], t);
        h[j] = fmaxf(t, 0.f);
    }
    float er[16];
#pragma unroll
    for (int j = 0; j < 16; j++) {
        float t = eb2[j];
#pragma unroll
        for (int i = 0; i < 32; i++) t = fmaf(h[i], eW2[i * 16 + j], t);
        er[j] = 1.f / (1.f + __expf(-t));
    }
    uint4* qo = (uint4*)(er_s + (size_t)p * 16);
    qo[0] = pack8bf(er);
    qo[1] = pack8bf(er + 8);
}

// ---- per-(node, k-slot) Y precompute: grid.y = 18 slots ----
// k<16: Y[n,k,:]; k==16: Y bias slot = x@B; k==17: root = x@rootW + rootB (fp32)
template <int IN>
__global__ __launch_bounds__(BS) void ynode_kernel(const float* __restrict__ x,
                                                   const float* __restrict__ W,   // [3][16][IN*8]
                                                   const float* __restrict__ B,   // [3][IN*8]
                                                   const float* __restrict__ RW,  // [3][IN][8]
                                                   const float* __restrict__ RB,  // [3][8]
                                                   unsigned short* __restrict__ Y,
                                                   float* __restrict__ root, int N)
{
    int n = blockIdx.x * BS + threadIdx.x;
    int k = blockIdx.y;            // 0..17, block-uniform
    bool valid = n < N;
    int nn = valid ? n : 0;
    float xv[IN];
#pragma unroll
    for (int i = 0; i < IN; i += 4)
        *(float4*)(xv + i) = *(const float4*)(x + (size_t)nn * IN + i);

    float r[24];
#pragma unroll
    for (int j = 0; j < 24; j++) r[j] = 0.f;

    if (k < 16) {
        const float* w = W + (size_t)k * (IN * 8);
#pragma unroll
        for (int a = 0; a < 3; a++) {
            const float* wa = w + (size_t)a * (16 * IN * 8);
#pragma unroll
            for (int i = 0; i < IN; i++) {
                float xi = xv[i];
#pragma unroll
                for (int o = 0; o < 8; o++)
                    r[a * 8 + o] = fmaf(xi, wa[i * 8 + o], r[a * 8 + o]);
            }
        }
        if (valid) st24bf(Y + (size_t)n * 408 + k * 24, r);
    } else if (k == 16) {
#pragma unroll
        for (int a = 0; a < 3; a++) {
            const float* ba = B + (size_t)a * (IN * 8);
#pragma unroll
            for (int i = 0; i < IN; i++) {
                float xi = xv[i];
#pragma unroll
                for (int o = 0; o < 8; o++)
                    r[a * 8 + o] = fmaf(xi, ba[i * 8 + o], r[a * 8 + o]);
            }
        }
        if (valid) st24bf(Y + (size_t)n * 408 + 16 * 24, r);
    } else {  // root transform, fp32
#pragma unroll
        for (int j = 0; j < 24; j++) r[j] = RB[j];
#pragma unroll
        for (int a = 0; a < 3; a++) {
            const float* wa = RW + (size_t)a * (IN * 8);
#pragma unroll
            for (int i = 0; i < IN; i++) {
                float xi = xv[i];
#pragma unroll
                for (int o = 0; o < 8; o++)
                    r[a * 8 + o] = fmaf(xi, wa[i * 8 + o], r[a * 8 + o]);
            }
        }
        if (valid) {
            float* pr = root + (size_t)n * 24;
#pragma unroll
            for (int j = 0; j < 24; j += 4)
                *(float4*)(pr + j) = make_float4(r[j], r[j + 1], r[j + 2], r[j + 3]);
        }
    }
}

// ---- per-(edge, 8-col part) msg: src-order compute (Y locality), bf16 write at dst slot ----
__global__ __launch_bounds__(BS) void msg_kernel(
    const uint2* __restrict__ spq,
    const unsigned short* __restrict__ er_s,   // [E][16] bf16, src-sorted
    const unsigned short* __restrict__ Y,
    unsigned short* __restrict__ msg16,        // [E][24] bf16, dst-sorted
    int E)
{
    int tid = blockIdx.x * BS + threadIdx.x;
    int p = tid / 3;
    int j = tid - p * 3;
    if (p >= E) return;

    uint2 sq = spq[p];

    float er[16];
    {
        const uint4* eu = (const uint4*)(er_s + (size_t)p * 16);
        unpack8(eu[0], er);
        unpack8(eu[1], er + 8);
    }

    const uint4* yu = (const uint4*)(Y + (size_t)sq.x * 408) + j;

    float acc[8];
    unpack8(yu[48], acc);         // bias slot
#pragma unroll
    for (int k = 0; k < 16; k++) {
        float t[8];
        unpack8(yu[k * 3], t);
        float ek = er[k];
#pragma unroll
        for (int o = 0; o < 8; o++) acc[o] = fmaf(ek, t[o], acc[o]);
    }
    *(uint4*)(msg16 + (size_t)sq.y * 24 + j * 8) = pack8bf(acc);
}

// ---- wave-per-node gather: 16-row x 48B bf16 tiles, shfl-reduce, add root ----
__global__ __launch_bounds__(BS) void gather_kernel(
    const unsigned short* __restrict__ msg16,  // [E][24] bf16, dst-sorted
    const int* __restrict__ offs,
    const int* __restrict__ degi,
    const float* __restrict__ root,            // [N][24] fp32
    float* __restrict__ out, int N)
{
    int n = (blockIdx.x * BS + threadIdx.x) >> 6;   // one wave per node
    if (n >= N) return;
    int lane = threadIdx.x & 63;
    int c = lane & 3;     // uint4-chunk 0..3 (0..2 active)
    int r = lane >> 2;    // row within 16-row tile

    int off = offs[n];
    int d = degi[n];

    float s[8], m[8];
#pragma unroll
    for (int o = 0; o < 8; o++) { s[o] = 0.f; m[o] = -3.402823466e38f; }

    if (c < 3) {
        const unsigned short* base = msg16 + (size_t)off * 24 + c * 8;
        for (int j = r; j < d; j += 16) {
            uint4 v = *(const uint4*)(base + (size_t)j * 24);
            float t[8];
            unpack8(v, t);
#pragma unroll
            for (int o = 0; o < 8; o++) {
                s[o] += t[o];
                m[o] = fmaxf(m[o], t[o]);
            }
        }
    }
    // reduce across rows: masks 4,8,16,32 (lanes with same c combine)
#pragma unroll
    for (int mask = 4; mask < 64; mask <<= 1) {
#pragma unroll
        for (int o = 0; o < 8; o++) {
            s[o] += __shfl_xor(s[o], mask);
            m[o] = fmaxf(m[o], __shfl_xor(m[o], mask));
        }
    }
    if (lane >= 3) return;   // lanes 0,1,2 hold aggregator c = lane

    float inv = 1.f / fmaxf((float)d, 1.f);
    const float* pr = root + (size_t)n * 24 + c * 8;
    float4 r0 = *(const float4*)(pr);
    float4 r1 = *(const float4*)(pr + 4);
    float rb[8] = {r0.x, r0.y, r0.z, r0.w, r1.x, r1.y, r1.z, r1.w};
    float rr[8];
#pragma unroll
    for (int o = 0; o < 8; o++) {
        float agg = (c == 0) ? s[o] * inv
                  : (c == 1) ? ((d > 0) ? m[o] : 0.f)
                  : s[o];
        rr[o] = fmaxf(rb[o] + agg, 0.f);
    }
    float* po = out + (size_t)n * 24 + c * 8;
    *(float4*)(po)     = make_float4(rr[0], rr[1], rr[2], rr[3]);
    *(float4*)(po + 4) = make_float4(rr[4], rr[5], rr[6], rr[7]);
}

// ---- output head ----
__global__ void head_kernel(const float* __restrict__ x, const float* __restrict__ W,
                            const float* __restrict__ b, float* __restrict__ out, int N)
{
    int n = blockIdx.x * blockDim.x + threadIdx.x;
    if (n >= N) return;
    float l0 = b[0], l1 = b[1];
#pragma unroll
    for (int i = 0; i < 24; i++) {
        float xi = x[(size_t)n * 24 + i];
        l0 = fmaf(xi, W[i * 2 + 0], l0);
        l1 = fmaf(xi, W[i * 2 + 1], l1);
    }
    out[2 * (size_t)n + 0] = l0;
    out[2 * (size_t)n + 1] = l1;
    float mx = fmaxf(l0, l1);
    float e0 = __expf(l0 - mx), e1 = __expf(l1 - mx);
    float sm = e0 + e1;
    out[2 * (size_t)N + 2 * (size_t)n + 0] = e0 / sm;
    out[2 * (size_t)N + 2 * (size_t)n + 1] = e1 / sm;
}

extern "C" void kernel_launch(void* const* d_in, const int* in_sizes, int n_in,
                              void* d_out, int out_size, void* d_ws, size_t ws_size,
                              hipStream_t stream)
{
    const float* x_feat = (const float*)d_in[0];
    const int*   eidx   = (const int*)d_in[1];
    const float* eattr  = (const float*)d_in[2];
    const float* lpW = (const float*)d_in[3];
    const float* lpb = (const float*)d_in[4];
    const float* tW  = (const float*)d_in[5];
    const float* tb  = (const float*)d_in[6];
    const float* eW1 = (const float*)d_in[7];
    const float* eb1 = (const float*)d_in[8];
    const float* eW2 = (const float*)d_in[9];
    const float* eb2 = (const float*)d_in[10];
    const float* c1W = (const float*)d_in[11];
    const float* c1B = (const float*)d_in[12];
    const float* c1R = (const float*)d_in[13];
    const float* c1b = (const float*)d_in[14];
    const float* c2W = (const float*)d_in[15];
    const float* c2B = (const float*)d_in[16];
    const float* c2R = (const float*)d_in[17];
    const float* c2b = (const float*)d_in[18];
    const float* oW  = (const float*)d_in[19];
    const float* ob  = (const float*)d_in[20];

    int N = in_sizes[0] / 24;
    int E = in_sizes[1] / 2;
    const int* srcA = eidx;
    const int* dstA = eidx + E;

    char* wsb = (char*)d_ws;
    size_t off = 0;
    auto alloc = [&](size_t bytes) {
        off = (off + 255) & ~(size_t)255;
        void* p = wsb + off;
        off += bytes;
        return p;
    };
    unsigned short* Y     = (unsigned short*)alloc((size_t)N * 408 * 2);
    unsigned short* msg16 = (unsigned short*)alloc((size_t)E * 24 * 2);
    unsigned short* er_s  = (unsigned short*)alloc((size_t)E * 16 * 2);
    float* root = (float*)alloc((size_t)N * 24 * 4);
    float* x16  = (float*)alloc((size_t)N * 16 * 4);
    float* x24a = (float*)alloc((size_t)N * 24 * 4);
    float* x24b = (float*)alloc((size_t)N * 24 * 4);
    int* ibase  = (int*)alloc(((size_t)2 * N + 2) * 4);  // cntS | cntD | cursS | cursD (zeroed)
    int* cntS = ibase;
    int* cntD = ibase + N;
    int* cursS = ibase + 2 * N;
    int* cursD = ibase + 2 * N + 1;
    int* offsS = (int*)alloc((size_t)N * 4);
    int* offsD = (int*)alloc((size_t)N * 4);
    int* jS    = (int*)alloc((size_t)E * 4);
    int* jD    = (int*)alloc((size_t)E * 4);
    uint2* spq = (uint2*)alloc((size_t)E * 8);

    dim3 blk(BS);
    int nb_nodes = (N + BS - 1) / BS;
    int nb_edges = (E + BS - 1) / BS;
    int nb_msg   = (3 * E + BS - 1) / BS;
    int nb_gath  = ((size_t)N * 64 + BS - 1) / BS;   // one wave per node
    dim3 ygrid(nb_nodes, 18);

    hipMemsetAsync(ibase, 0, (2 * (size_t)N + 2) * 4, stream);

    prep_kernel<<<nb_nodes, blk, 0, stream>>>(x_feat, lpW, lpb, tW, tb, x16, N);

    degjj_kernel<<<nb_edges, blk, 0, stream>>>(srcA, dstA, cntS, cntD, jS, jD, E);
    offsets2_kernel<<<nb_nodes, blk, 0, stream>>>(cntS, cntD, offsS, offsD, cursS, cursD, N);
    er_fill_kernel<<<nb_edges, blk, 0, stream>>>(srcA, dstA, jS, jD, offsS, offsD,
                                                 eattr, eW1, eb1, eW2, eb2, spq, er_s, E);

    // ---- conv1 ----
    ynode_kernel<16><<<ygrid, blk, 0, stream>>>(x16, c1W, c1B, c1R, c1b, Y, root, N);
    msg_kernel<<<nb_msg, blk, 0, stream>>>(spq, er_s, Y, msg16, E);
    gather_kernel<<<nb_gath, blk, 0, stream>>>(msg16, offsD, cntD, root, x24a, N);

    // ---- conv2 ----
    ynode_kernel<24><<<ygrid, blk, 0, stream>>>(x24a, c2W, c2B, c2R, c2b, Y, root, N);
    msg_kernel<<<nb_msg, blk, 0, stream>>>(spq, er_s, Y, msg16, E);
    gather_kernel<<<nb_gath, blk, 0, stream>>>(msg16, offsD, cntD, root, x24b, N);

    head_kernel<<<nb_nodes, blk, 0, stream>>>(x24b, oW, ob, (float*)d_out, N);
}

// Round 11
// 286.885 us; speedup vs baseline: 4.8597x; 1.0309x over previous
//
#include <hip/hip_runtime.h>

#define BS 256

// ---------------- bf16 helpers ----------------
__device__ __forceinline__ unsigned short f2bf(float f) {
    unsigned x = __float_as_uint(f);
    return (unsigned short)((x + 0x7fffu + ((x >> 16) & 1u)) >> 16);
}
__device__ __forceinline__ void unpack8(uint4 v, float* d) {
    d[0] = __uint_as_float(v.x << 16); d[1] = __uint_as_float(v.x & 0xFFFF0000u);
    d[2] = __uint_as_float(v.y << 16); d[3] = __uint_as_float(v.y & 0xFFFF0000u);
    d[4] = __uint_as_float(v.z << 16); d[5] = __uint_as_float(v.z & 0xFFFF0000u);
    d[6] = __uint_as_float(v.w << 16); d[7] = __uint_as_float(v.w & 0xFFFF0000u);
}
__device__ __forceinline__ uint4 pack8bf(const float* r) {
    unsigned w[4];
#pragma unroll
    for (int j = 0; j < 4; j++)
        w[j] = (unsigned)f2bf(r[2 * j]) | ((unsigned)f2bf(r[2 * j + 1]) << 16);
    return make_uint4(w[0], w[1], w[2], w[3]);
}
// store 24 floats as 24 bf16 (48 B = 3x uint4)
__device__ __forceinline__ void st24bf(unsigned short* p, const float* r) {
    uint4* q = (uint4*)p;
    q[0] = pack8bf(r);
    q[1] = pack8bf(r + 8);
    q[2] = pack8bf(r + 16);
}

// ---- node prep: x16 = relu(relu(x_feat @ lpW + lpb) @ tW + tb) ----
__global__ void prep_kernel(const float* __restrict__ xf,
                            const float* __restrict__ W1, const float* __restrict__ b1,
                            const float* __restrict__ W2, const float* __restrict__ b2,
                            float* __restrict__ x16, int N)
{
    int n = blockIdx.x * blockDim.x + threadIdx.x;
    bool valid = n < N;
    int nn = valid ? n : 0;
    float a[24];
#pragma unroll
    for (int i = 0; i < 24; i += 4)
        *(float4*)(a + i) = *(const float4*)(xf + (size_t)nn * 24 + i);
    float h[32];
#pragma unroll
    for (int j = 0; j < 32; j++) {
        float s = b1[j];
#pragma unroll
        for (int i = 0; i < 24; i++) s = fmaf(a[i], W1[i * 32 + j], s);
        h[j] = fmaxf(s, 0.f);
    }
    if (!valid) return;
#pragma unroll
    for (int j = 0; j < 16; j++) {
        float s = b2[j];
#pragma unroll
        for (int i = 0; i < 32; i++) s = fmaf(h[i], W2[i * 16 + j], s);
        x16[(size_t)n * 16 + j] = fmaxf(s, 0.f);
    }
}

// ---- counting pass: histogram both sides, store occurrence index per edge ----
__global__ void degjj_kernel(const int* __restrict__ srcA, const int* __restrict__ dstA,
                             int* __restrict__ cntS, int* __restrict__ cntD,
                             int* __restrict__ jS, int* __restrict__ jD, int E)
{
    int e = blockIdx.x * blockDim.x + threadIdx.x;
    if (e < E) {
        jS[e] = atomicAdd(&cntS[srcA[e]], 1);
        jD[e] = atomicAdd(&cntD[dstA[e]], 1);
    }
}
// wave-scan offsets: 1 cursor atomic per wave
__global__ void offsets2_kernel(const int* __restrict__ cntS, const int* __restrict__ cntD,
                                int* __restrict__ offsS, int* __restrict__ offsD,
                                int* __restrict__ cursS, int* __restrict__ cursD, int N)
{
    int n = blockIdx.x * blockDim.x + threadIdx.x;
    int lane = threadIdx.x & 63;
    bool valid = n < N;
    int dS = valid ? cntS[n] : 0;
    int dD = valid ? cntD[n] : 0;
    int sS = dS, sD = dD;
#pragma unroll
    for (int o = 1; o < 64; o <<= 1) {
        int tS = __shfl_up(sS, o);
        int tD = __shfl_up(sD, o);
        if (lane >= o) { sS += tS; sD += tD; }
    }
    int totS = __shfl(sS, 63);
    int totD = __shfl(sD, 63);
    int baseS = 0, baseD = 0;
    if (lane == 63) {
        baseS = atomicAdd(cursS, totS);
        baseD = atomicAdd(cursD, totD);
    }
    baseS = __shfl(baseS, 63);
    baseD = __shfl(baseD, 63);
    if (valid) {
        offsS[n] = baseS + sS - dS;
        offsD[n] = baseD + sD - dD;
    }
}

// ---- fused fill + edge trunk: coalesced eattr, no atomics ----
// p = offsS[s]+jS[e] (src-sorted row), q = offsD[d]+jD[e] (dst-sorted msg row)
__global__ __launch_bounds__(BS) void er_fill_kernel(
    const int* __restrict__ srcA, const int* __restrict__ dstA,
    const int* __restrict__ jS, const int* __restrict__ jD,
    const int* __restrict__ offsS, const int* __restrict__ offsD,
    const float* __restrict__ eattr,
    const float* __restrict__ eW1, const float* __restrict__ eb1,
    const float* __restrict__ eW2, const float* __restrict__ eb2,
    uint2* __restrict__ spq, unsigned short* __restrict__ er_s, int E)
{
    int e = blockIdx.x * BS + threadIdx.x;
    if (e >= E) return;
    int s = srcA[e], d = dstA[e];
    int p = offsS[s] + jS[e];
    int q = offsD[d] + jD[e];
    spq[p] = make_uint2((unsigned)s, (unsigned)q);

    float ea[16];
#pragma unroll
    for (int i = 0; i < 16; i += 4)
        *(float4*)(ea + i) = *(const float4*)(eattr + (size_t)e * 16 + i);
    float h[32];
#pragma unroll
    for (int j = 0; j < 32; j++) {
        float t = eb1[j];
#pragma unroll
        for (int i = 0; i < 16; i++) t = fmaf(ea[i], eW1[i * 32 + j], t);
        h[j] = fmaxf(t, 0.f);
    }
    float er[16];
#pragma unroll
    for (int j = 0; j < 16; j++) {
        float t = eb2[j];
#pragma unroll
        for (int i = 0; i < 32; i++) t = fmaf(h[i], eW2[i * 16 + j], t);
        er[j] = 1.f / (1.f + __expf(-t));
    }
    uint4* qo = (uint4*)(er_s + (size_t)p * 16);
    qo[0] = pack8bf(er);
    qo[1] = pack8bf(er + 8);
}

// ---- per-(node, k-slot) Y precompute, k-major layout Y[k][N][24] ----
// k<16: Y[k][n][:] = x @ W[:,k,:]; k==16: bias slot = x@B; k==17: root = x@rootW+rootB (fp32)
template <int IN>
__global__ __launch_bounds__(BS) void ynode_kernel(const float* __restrict__ x,
                                                   const float* __restrict__ W,   // [3][16][IN*8]
                                                   const float* __restrict__ B,   // [3][IN*8]
                                                   const float* __restrict__ RW,  // [3][IN][8]
                                                   const float* __restrict__ RB,  // [3][8]
                                                   unsigned short* __restrict__ Y,
                                                   float* __restrict__ root, int N)
{
    int n = blockIdx.x * BS + threadIdx.x;
    int k = blockIdx.y;            // 0..17, block-uniform
    bool valid = n < N;
    int nn = valid ? n : 0;
    float xv[IN];
#pragma unroll
    for (int i = 0; i < IN; i += 4)
        *(float4*)(xv + i) = *(const float4*)(x + (size_t)nn * IN + i);

    float r[24];
#pragma unroll
    for (int j = 0; j < 24; j++) r[j] = 0.f;

    if (k < 16) {
        const float* w = W + (size_t)k * (IN * 8);
#pragma unroll
        for (int a = 0; a < 3; a++) {
            const float* wa = w + (size_t)a * (16 * IN * 8);
#pragma unroll
            for (int i = 0; i < IN; i++) {
                float xi = xv[i];
#pragma unroll
                for (int o = 0; o < 8; o++)
                    r[a * 8 + o] = fmaf(xi, wa[i * 8 + o], r[a * 8 + o]);
            }
        }
        if (valid) st24bf(Y + ((size_t)k * N + n) * 24, r);   // coalesced: lanes adjacent
    } else if (k == 16) {
#pragma unroll
        for (int a = 0; a < 3; a++) {
            const float* ba = B + (size_t)a * (IN * 8);
#pragma unroll
            for (int i = 0; i < IN; i++) {
                float xi = xv[i];
#pragma unroll
                for (int o = 0; o < 8; o++)
                    r[a * 8 + o] = fmaf(xi, ba[i * 8 + o], r[a * 8 + o]);
            }
        }
        if (valid) st24bf(Y + ((size_t)16 * N + n) * 24, r);
    } else {  // root transform, fp32
#pragma unroll
        for (int j = 0; j < 24; j++) r[j] = RB[j];
#pragma unroll
        for (int a = 0; a < 3; a++) {
            const float* wa = RW + (size_t)a * (IN * 8);
#pragma unroll
            for (int i = 0; i < IN; i++) {
                float xi = xv[i];
#pragma unroll
                for (int o = 0; o < 8; o++)
                    r[a * 8 + o] = fmaf(xi, wa[i * 8 + o], r[a * 8 + o]);
            }
        }
        if (valid) {
            float* pr = root + (size_t)n * 24;
#pragma unroll
            for (int j = 0; j < 24; j += 4)
                *(float4*)(pr + j) = make_float4(r[j], r[j + 1], r[j + 2], r[j + 3]);
        }
    }
}

// ---- per-(edge, 8-col part) msg: src-order compute, k-major Y reads, bf16 write at dst slot ----
__global__ __launch_bounds__(BS) void msg_kernel(
    const uint2* __restrict__ spq,
    const unsigned short* __restrict__ er_s,   // [E][16] bf16, src-sorted
    const unsigned short* __restrict__ Y,      // [17][N][24] bf16
    unsigned short* __restrict__ msg16,        // [E][24] bf16, dst-sorted
    int N, int E)
{
    int tid = blockIdx.x * BS + threadIdx.x;
    int p = tid / 3;
    int j = tid - p * 3;
    if (p >= E) return;

    uint2 sq = spq[p];

    float er[16];
    {
        const uint4* eu = (const uint4*)(er_s + (size_t)p * 16);
        unpack8(eu[0], er);
        unpack8(eu[1], er + 8);
    }

    const unsigned short* yb = Y + (size_t)sq.x * 24 + j * 8;
    size_t kstride = (size_t)N * 24;

    float acc[8];
    unpack8(*(const uint4*)(yb + 16 * kstride), acc);   // bias slot
#pragma unroll
    for (int k = 0; k < 16; k++) {
        float t[8];
        unpack8(*(const uint4*)(yb + (size_t)k * kstride), t);
        float ek = er[k];
#pragma unroll
        for (int o = 0; o < 8; o++) acc[o] = fmaf(ek, t[o], acc[o]);
    }
    *(uint4*)(msg16 + (size_t)sq.y * 24 + j * 8) = pack8bf(acc);
}

// ---- wave-per-node gather: 16-row x 48B bf16 tiles, shfl-reduce, add root ----
__global__ __launch_bounds__(BS) void gather_kernel(
    const unsigned short* __restrict__ msg16,  // [E][24] bf16, dst-sorted
    const int* __restrict__ offs,
    const int* __restrict__ degi,
    const float* __restrict__ root,            // [N][24] fp32
    float* __restrict__ out, int N)
{
    int n = (blockIdx.x * BS + threadIdx.x) >> 6;   // one wave per node
    if (n >= N) return;
    int lane = threadIdx.x & 63;
    int c = lane & 3;     // uint4-chunk 0..3 (0..2 active)
    int r = lane >> 2;    // row within 16-row tile

    int off = offs[n];
    int d = degi[n];

    float s[8], m[8];
#pragma unroll
    for (int o = 0; o < 8; o++) { s[o] = 0.f; m[o] = -3.402823466e38f; }

    if (c < 3) {
        const unsigned short* base = msg16 + (size_t)off * 24 + c * 8;
        for (int j = r; j < d; j += 16) {
            uint4 v = *(const uint4*)(base + (size_t)j * 24);
            float t[8];
            unpack8(v, t);
#pragma unroll
            for (int o = 0; o < 8; o++) {
                s[o] += t[o];
                m[o] = fmaxf(m[o], t[o]);
            }
        }
    }
    // reduce across rows: masks 4,8,16,32 (lanes with same c combine)
#pragma unroll
    for (int mask = 4; mask < 64; mask <<= 1) {
#pragma unroll
        for (int o = 0; o < 8; o++) {
            s[o] += __shfl_xor(s[o], mask);
            m[o] = fmaxf(m[o], __shfl_xor(m[o], mask));
        }
    }
    if (lane >= 3) return;   // lanes 0,1,2 hold aggregator c = lane

    float inv = 1.f / fmaxf((float)d, 1.f);
    const float* pr = root + (size_t)n * 24 + c * 8;
    float4 r0 = *(const float4*)(pr);
    float4 r1 = *(const float4*)(pr + 4);
    float rb[8] = {r0.x, r0.y, r0.z, r0.w, r1.x, r1.y, r1.z, r1.w};
    float rr[8];
#pragma unroll
    for (int o = 0; o < 8; o++) {
        float agg = (c == 0) ? s[o] * inv
                  : (c == 1) ? ((d > 0) ? m[o] : 0.f)
                  : s[o];
        rr[o] = fmaxf(rb[o] + agg, 0.f);
    }
    float* po = out + (size_t)n * 24 + c * 8;
    *(float4*)(po)     = make_float4(rr[0], rr[1], rr[2], rr[3]);
    *(float4*)(po + 4) = make_float4(rr[4], rr[5], rr[6], rr[7]);
}

// ---- output head ----
__global__ void head_kernel(const float* __restrict__ x, const float* __restrict__ W,
                            const float* __restrict__ b, float* __restrict__ out, int N)
{
    int n = blockIdx.x * blockDim.x + threadIdx.x;
    if (n >= N) return;
    float l0 = b[0], l1 = b[1];
#pragma unroll
    for (int i = 0; i < 24; i++) {
        float xi = x[(size_t)n * 24 + i];
        l0 = fmaf(xi, W[i * 2 + 0], l0);
        l1 = fmaf(xi, W[i * 2 + 1], l1);
    }
    out[2 * (size_t)n + 0] = l0;
    out[2 * (size_t)n + 1] = l1;
    float mx = fmaxf(l0, l1);
    float e0 = __expf(l0 - mx), e1 = __expf(l1 - mx);
    float sm = e0 + e1;
    out[2 * (size_t)N + 2 * (size_t)n + 0] = e0 / sm;
    out[2 * (size_t)N + 2 * (size_t)n + 1] = e1 / sm;
}

extern "C" void kernel_launch(void* const* d_in, const int* in_sizes, int n_in,
                              void* d_out, int out_size, void* d_ws, size_t ws_size,
                              hipStream_t stream)
{
    const float* x_feat = (const float*)d_in[0];
    const int*   eidx   = (const int*)d_in[1];
    const float* eattr  = (const float*)d_in[2];
    const float* lpW = (const float*)d_in[3];
    const float* lpb = (const float*)d_in[4];
    const float* tW  = (const float*)d_in[5];
    const float* tb  = (const float*)d_in[6];
    const float* eW1 = (const float*)d_in[7];
    const float* eb1 = (const float*)d_in[8];
    const float* eW2 = (const float*)d_in[9];
    const float* eb2 = (const float*)d_in[10];
    const float* c1W = (const float*)d_in[11];
    const float* c1B = (const float*)d_in[12];
    const float* c1R = (const float*)d_in[13];
    const float* c1b = (const float*)d_in[14];
    const float* c2W = (const float*)d_in[15];
    const float* c2B = (const float*)d_in[16];
    const float* c2R = (const float*)d_in[17];
    const float* c2b = (const float*)d_in[18];
    const float* oW  = (const float*)d_in[19];
    const float* ob  = (const float*)d_in[20];

    int N = in_sizes[0] / 24;
    int E = in_sizes[1] / 2;
    const int* srcA = eidx;
    const int* dstA = eidx + E;

    char* wsb = (char*)d_ws;
    size_t off = 0;
    auto alloc = [&](size_t bytes) {
        off = (off + 255) & ~(size_t)255;
        void* p = wsb + off;
        off += bytes;
        return p;
    };
    unsigned short* Y     = (unsigned short*)alloc((size_t)17 * N * 24 * 2);
    unsigned short* msg16 = (unsigned short*)alloc((size_t)E * 24 * 2);
    unsigned short* er_s  = (unsigned short*)alloc((size_t)E * 16 * 2);
    float* root = (float*)alloc((size_t)N * 24 * 4);
    float* x16  = (float*)alloc((size_t)N * 16 * 4);
    float* x24a = (float*)alloc((size_t)N * 24 * 4);
    float* x24b = (float*)alloc((size_t)N * 24 * 4);
    int* ibase  = (int*)alloc(((size_t)2 * N + 2) * 4);  // cntS | cntD | cursS | cursD (zeroed)
    int* cntS = ibase;
    int* cntD = ibase + N;
    int* cursS = ibase + 2 * N;
    int* cursD = ibase + 2 * N + 1;
    int* offsS = (int*)alloc((size_t)N * 4);
    int* offsD = (int*)alloc((size_t)N * 4);
    int* jS    = (int*)alloc((size_t)E * 4);
    int* jD    = (int*)alloc((size_t)E * 4);
    uint2* spq = (uint2*)alloc((size_t)E * 8);

    dim3 blk(BS);
    int nb_nodes = (N + BS - 1) / BS;
    int nb_edges = (E + BS - 1) / BS;
    int nb_msg   = (3 * E + BS - 1) / BS;
    int nb_gath  = ((size_t)N * 64 + BS - 1) / BS;   // one wave per node
    dim3 ygrid(nb_nodes, 18);

    hipMemsetAsync(ibase, 0, (2 * (size_t)N + 2) * 4, stream);

    prep_kernel<<<nb_nodes, blk, 0, stream>>>(x_feat, lpW, lpb, tW, tb, x16, N);

    degjj_kernel<<<nb_edges, blk, 0, stream>>>(srcA, dstA, cntS, cntD, jS, jD, E);
    offsets2_kernel<<<nb_nodes, blk, 0, stream>>>(cntS, cntD, offsS, offsD, cursS, cursD, N);
    er_fill_kernel<<<nb_edges, blk, 0, stream>>>(srcA, dstA, jS, jD, offsS, offsD,
                                                 eattr, eW1, eb1, eW2, eb2, spq, er_s, E);

    // ---- conv1 ----
    ynode_kernel<16><<<ygrid, blk, 0, stream>>>(x16, c1W, c1B, c1R, c1b, Y, root, N);
    msg_kernel<<<nb_msg, blk, 0, stream>>>(spq, er_s, Y, msg16, N, E);
    gather_kernel<<<nb_gath, blk, 0, stream>>>(msg16, offsD, cntD, root, x24a, N);

    // ---- conv2 ----
    ynode_kernel<24><<<ygrid, blk, 0, stream>>>(x24a, c2W, c2B, c2R, c2b, Y, root, N);
    msg_kernel<<<nb_msg, blk, 0, stream>>>(spq, er_s, Y, msg16, N, E);
    gather_kernel<<<nb_gath, blk, 0, stream>>>(msg16, offsD, cntD, root, x24b, N);

    head_kernel<<<nb_nodes, blk, 0, stream>>>(x24b, oW, ob, (float*)d_out, N);
}

// Round 12
// 276.250 us; speedup vs baseline: 5.0468x; 1.0385x over previous
//
#include <hip/hip_runtime.h>

#define BS 256

// ---------------- bf16 helpers ----------------
__device__ __forceinline__ unsigned short f2bf(float f) {
    unsigned x = __float_as_uint(f);
    return (unsigned short)((x + 0x7fffu + ((x >> 16) & 1u)) >> 16);
}
__device__ __forceinline__ void unpack8(uint4 v, float* d) {
    d[0] = __uint_as_float(v.x << 16); d[1] = __uint_as_float(v.x & 0xFFFF0000u);
    d[2] = __uint_as_float(v.y << 16); d[3] = __uint_as_float(v.y & 0xFFFF0000u);
    d[4] = __uint_as_float(v.z << 16); d[5] = __uint_as_float(v.z & 0xFFFF0000u);
    d[6] = __uint_as_float(v.w << 16); d[7] = __uint_as_float(v.w & 0xFFFF0000u);
}
__device__ __forceinline__ uint4 pack8bf(const float* r) {
    unsigned w[4];
#pragma unroll
    for (int j = 0; j < 4; j++)
        w[j] = (unsigned)f2bf(r[2 * j]) | ((unsigned)f2bf(r[2 * j + 1]) << 16);
    return make_uint4(w[0], w[1], w[2], w[3]);
}
// store 24 floats as 24 bf16 (48 B = 3x uint4)
__device__ __forceinline__ void st24bf(unsigned short* p, const float* r) {
    uint4* q = (uint4*)p;
    q[0] = pack8bf(r);
    q[1] = pack8bf(r + 8);
    q[2] = pack8bf(r + 16);
}

// ---- node prep: x16 = relu(relu(x_feat @ lpW + lpb) @ tW + tb) ----
__global__ void prep_kernel(const float* __restrict__ xf,
                            const float* __restrict__ W1, const float* __restrict__ b1,
                            const float* __restrict__ W2, const float* __restrict__ b2,
                            float* __restrict__ x16, int N)
{
    int n = blockIdx.x * blockDim.x + threadIdx.x;
    bool valid = n < N;
    int nn = valid ? n : 0;
    float a[24];
#pragma unroll
    for (int i = 0; i < 24; i += 4)
        *(float4*)(a + i) = *(const float4*)(xf + (size_t)nn * 24 + i);
    float h[32];
#pragma unroll
    for (int j = 0; j < 32; j++) {
        float s = b1[j];
#pragma unroll
        for (int i = 0; i < 24; i++) s = fmaf(a[i], W1[i * 32 + j], s);
        h[j] = fmaxf(s, 0.f);
    }
    if (!valid) return;
#pragma unroll
    for (int j = 0; j < 16; j++) {
        float s = b2[j];
#pragma unroll
        for (int i = 0; i < 32; i++) s = fmaf(h[i], W2[i * 16 + j], s);
        x16[(size_t)n * 16 + j] = fmaxf(s, 0.f);
    }
}

// ---- counting pass: histogram both sides, store occurrence index per edge ----
__global__ void degjj_kernel(const int* __restrict__ srcA, const int* __restrict__ dstA,
                             int* __restrict__ cntS, int* __restrict__ cntD,
                             int* __restrict__ jS, int* __restrict__ jD, int E)
{
    int e = blockIdx.x * blockDim.x + threadIdx.x;
    if (e < E) {
        jS[e] = atomicAdd(&cntS[srcA[e]], 1);
        jD[e] = atomicAdd(&cntD[dstA[e]], 1);
    }
}
// wave-scan offsets: 1 cursor atomic per wave
__global__ void offsets2_kernel(const int* __restrict__ cntS, const int* __restrict__ cntD,
                                int* __restrict__ offsS, int* __restrict__ offsD,
                                int* __restrict__ cursS, int* __restrict__ cursD, int N)
{
    int n = blockIdx.x * blockDim.x + threadIdx.x;
    int lane = threadIdx.x & 63;
    bool valid = n < N;
    int dS = valid ? cntS[n] : 0;
    int dD = valid ? cntD[n] : 0;
    int sS = dS, sD = dD;
#pragma unroll
    for (int o = 1; o < 64; o <<= 1) {
        int tS = __shfl_up(sS, o);
        int tD = __shfl_up(sD, o);
        if (lane >= o) { sS += tS; sD += tD; }
    }
    int totS = __shfl(sS, 63);
    int totD = __shfl(sD, 63);
    int baseS = 0, baseD = 0;
    if (lane == 63) {
        baseS = atomicAdd(cursS, totS);
        baseD = atomicAdd(cursD, totD);
    }
    baseS = __shfl(baseS, 63);
    baseD = __shfl(baseD, 63);
    if (valid) {
        offsS[n] = baseS + sS - dS;
        offsD[n] = baseD + sD - dD;
    }
}

// ---- fused fill + edge trunk: coalesced eattr, no atomics ----
__global__ __launch_bounds__(BS) void er_fill_kernel(
    const int* __restrict__ srcA, const int* __restrict__ dstA,
    const int* __restrict__ jS, const int* __restrict__ jD,
    const int* __restrict__ offsS, const int* __restrict__ offsD,
    const float* __restrict__ eattr,
    const float* __restrict__ eW1, const float* __restrict__ eb1,
    const float* __restrict__ eW2, const float* __restrict__ eb2,
    uint2* __restrict__ spq, unsigned short* __restrict__ er_s, int E)
{
    int e = blockIdx.x * BS + threadIdx.x;
    if (e >= E) return;
    int s = srcA[e], d = dstA[e];
    int p = offsS[s] + jS[e];
    int q = offsD[d] + jD[e];
    spq[p] = make_uint2((unsigned)s, (unsigned)q);

    float ea[16];
#pragma unroll
    for (int i = 0; i < 16; i += 4)
        *(float4*)(ea + i) = *(const float4*)(eattr + (size_t)e * 16 + i);
    float h[32];
#pragma unroll
    for (int j = 0; j < 32; j++) {
        float t = eb1[j];
#pragma unroll
        for (int i = 0; i < 16; i++) t = fmaf(ea[i], eW1[i * 32 + j], t);
        h[j] = fmaxf(t, 0.f);
    }
    float er[16];
#pragma unroll
    for (int j = 0; j < 16; j++) {
        float t = eb2[j];
#pragma unroll
        for (int i = 0; i < 32; i++) t = fmaf(h[i], eW2[i * 16 + j], t);
        er[j] = 1.f / (1.f + __expf(-t));
    }
    uint4* qo = (uint4*)(er_s + (size_t)p * 16);
    qo[0] = pack8bf(er);
    qo[1] = pack8bf(er + 8);
}

// ---- per-(node-pair, k-slot) Y precompute: LDS-staged weights, 2 nodes/thread ----
// Y layout k-major [17][N][24]; k==17 -> root = x@rootW + rootB (fp32)
template <int IN>
__global__ __launch_bounds__(BS) void ynode_kernel(const float* __restrict__ x,
                                                   const float* __restrict__ W,   // [3][16][IN*8]
                                                   const float* __restrict__ B,   // [3][IN*8]
                                                   const float* __restrict__ RW,  // [3][IN][8]
                                                   const float* __restrict__ RB,  // [3][8]
                                                   unsigned short* __restrict__ Y,
                                                   float* __restrict__ root, int N)
{
    __shared__ float w_lds[IN * 24];
    int t = threadIdx.x;
    int k = blockIdx.y;            // 0..17, block-uniform

    // stage this k-slot's weights into LDS as [i][a*8+o]
    for (int idx = t; idx < IN * 24; idx += BS) {
        int i = idx / 24;
        int j = idx - i * 24;
        int a = j >> 3, o = j & 7;
        float v;
        if (k < 16)       v = W[(((size_t)a * 16 + k) * IN + i) * 8 + o];
        else if (k == 16) v = B[((size_t)a * IN + i) * 8 + o];
        else              v = RW[((size_t)a * IN + i) * 8 + o];
        w_lds[idx] = v;
    }
    __syncthreads();

    int n0 = blockIdx.x * (BS * 2) + t;
    int n1 = n0 + BS;
    bool v0 = n0 < N, v1 = n1 < N;
    int m0 = v0 ? n0 : 0, m1 = v1 ? n1 : 0;

    float xa[IN], xb[IN];
#pragma unroll
    for (int i = 0; i < IN; i += 4) {
        *(float4*)(xa + i) = *(const float4*)(x + (size_t)m0 * IN + i);
        *(float4*)(xb + i) = *(const float4*)(x + (size_t)m1 * IN + i);
    }

    float ra[24], rb[24];
    if (k == 17) {
#pragma unroll
        for (int j = 0; j < 24; j++) { ra[j] = RB[j]; rb[j] = ra[j]; }
    } else {
#pragma unroll
        for (int j = 0; j < 24; j++) { ra[j] = 0.f; rb[j] = 0.f; }
    }

#pragma unroll
    for (int i = 0; i < IN; i++) {
        float x0 = xa[i], x1 = xb[i];
        const float* wr = w_lds + i * 24;
#pragma unroll
        for (int j = 0; j < 24; j++) {
            float w = wr[j];
            ra[j] = fmaf(x0, w, ra[j]);
            rb[j] = fmaf(x1, w, rb[j]);
        }
    }

    if (k < 17) {
        if (v0) st24bf(Y + ((size_t)k * N + n0) * 24, ra);
        if (v1) st24bf(Y + ((size_t)k * N + n1) * 24, rb);
    } else {
        if (v0) {
            float* pr = root + (size_t)n0 * 24;
#pragma unroll
            for (int j = 0; j < 24; j += 4)
                *(float4*)(pr + j) = make_float4(ra[j], ra[j+1], ra[j+2], ra[j+3]);
        }
        if (v1) {
            float* pr = root + (size_t)n1 * 24;
#pragma unroll
            for (int j = 0; j < 24; j += 4)
                *(float4*)(pr + j) = make_float4(rb[j], rb[j+1], rb[j+2], rb[j+3]);
        }
    }
}

// ---- per-(edge, 8-col part) msg: src-order compute, k-major Y reads ----
// msg16 rows padded to 32 bf16 (64 B line-aligned); j==0 zero-fills the pad.
__global__ __launch_bounds__(BS) void msg_kernel(
    const uint2* __restrict__ spq,
    const unsigned short* __restrict__ er_s,   // [E][16] bf16, src-sorted
    const unsigned short* __restrict__ Y,      // [17][N][24] bf16
    unsigned short* __restrict__ msg16,        // [E][32] bf16, dst-sorted
    int N, int E)
{
    int tid = blockIdx.x * BS + threadIdx.x;
    int p = tid / 3;
    int j = tid - p * 3;
    if (p >= E) return;

    uint2 sq = spq[p];

    float er[16];
    {
        const uint4* eu = (const uint4*)(er_s + (size_t)p * 16);
        unpack8(eu[0], er);
        unpack8(eu[1], er + 8);
    }

    const unsigned short* yb = Y + (size_t)sq.x * 24 + j * 8;
    size_t kstride = (size_t)N * 24;

    float acc[8];
    unpack8(*(const uint4*)(yb + 16 * kstride), acc);   // bias slot
#pragma unroll
    for (int k = 0; k < 16; k++) {
        float t[8];
        unpack8(*(const uint4*)(yb + (size_t)k * kstride), t);
        float ek = er[k];
#pragma unroll
        for (int o = 0; o < 8; o++) acc[o] = fmaf(ek, t[o], acc[o]);
    }
    unsigned short* mrow = msg16 + (size_t)sq.y * 32;
    *(uint4*)(mrow + j * 8) = pack8bf(acc);
    if (j == 0) *(uint4*)(mrow + 24) = make_uint4(0, 0, 0, 0);  // fill line
}

// ---- wave-per-node gather: 16-row x 64B bf16 tiles, shfl-reduce, add root ----
__global__ __launch_bounds__(BS) void gather_kernel(
    const unsigned short* __restrict__ msg16,  // [E][32] bf16, dst-sorted
    const int* __restrict__ offs,
    const int* __restrict__ degi,
    const float* __restrict__ root,            // [N][24] fp32
    float* __restrict__ out, int N)
{
    int n = (blockIdx.x * BS + threadIdx.x) >> 6;   // one wave per node
    if (n >= N) return;
    int lane = threadIdx.x & 63;
    int c = lane & 3;     // uint4-chunk 0..3 (0..2 active)
    int r = lane >> 2;    // row within 16-row tile

    int off = offs[n];
    int d = degi[n];

    float s[8], m[8];
#pragma unroll
    for (int o = 0; o < 8; o++) { s[o] = 0.f; m[o] = -3.402823466e38f; }

    if (c < 3) {
        const unsigned short* base = msg16 + (size_t)off * 32 + c * 8;
        for (int j = r; j < d; j += 16) {
            uint4 v = *(const uint4*)(base + (size_t)j * 32);
            float t[8];
            unpack8(v, t);
#pragma unroll
            for (int o = 0; o < 8; o++) {
                s[o] += t[o];
                m[o] = fmaxf(m[o], t[o]);
            }
        }
    }
#pragma unroll
    for (int mask = 4; mask < 64; mask <<= 1) {
#pragma unroll
        for (int o = 0; o < 8; o++) {
            s[o] += __shfl_xor(s[o], mask);
            m[o] = fmaxf(m[o], __shfl_xor(m[o], mask));
        }
    }
    if (lane >= 3) return;   // lanes 0,1,2 hold aggregator c = lane

    float inv = 1.f / fmaxf((float)d, 1.f);
    const float* pr = root + (size_t)n * 24 + c * 8;
    float4 r0 = *(const float4*)(pr);
    float4 r1 = *(const float4*)(pr + 4);
    float rb[8] = {r0.x, r0.y, r0.z, r0.w, r1.x, r1.y, r1.z, r1.w};
    float rr[8];
#pragma unroll
    for (int o = 0; o < 8; o++) {
        float agg = (c == 0) ? s[o] * inv
                  : (c == 1) ? ((d > 0) ? m[o] : 0.f)
                  : s[o];
        rr[o] = fmaxf(rb[o] + agg, 0.f);
    }
    float* po = out + (size_t)n * 24 + c * 8;
    *(float4*)(po)     = make_float4(rr[0], rr[1], rr[2], rr[3]);
    *(float4*)(po + 4) = make_float4(rr[4], rr[5], rr[6], rr[7]);
}

// ---- output head ----
__global__ void head_kernel(const float* __restrict__ x, const float* __restrict__ W,
                            const float* __restrict__ b, float* __restrict__ out, int N)
{
    int n = blockIdx.x * blockDim.x + threadIdx.x;
    if (n >= N) return;
    float l0 = b[0], l1 = b[1];
#pragma unroll
    for (int i = 0; i < 24; i++) {
        float xi = x[(size_t)n * 24 + i];
        l0 = fmaf(xi, W[i * 2 + 0], l0);
        l1 = fmaf(xi, W[i * 2 + 1], l1);
    }
    out[2 * (size_t)n + 0] = l0;
    out[2 * (size_t)n + 1] = l1;
    float mx = fmaxf(l0, l1);
    float e0 = __expf(l0 - mx), e1 = __expf(l1 - mx);
    float sm = e0 + e1;
    out[2 * (size_t)N + 2 * (size_t)n + 0] = e0 / sm;
    out[2 * (size_t)N + 2 * (size_t)n + 1] = e1 / sm;
}

extern "C" void kernel_launch(void* const* d_in, const int* in_sizes, int n_in,
                              void* d_out, int out_size, void* d_ws, size_t ws_size,
                              hipStream_t stream)
{
    const float* x_feat = (const float*)d_in[0];
    const int*   eidx   = (const int*)d_in[1];
    const float* eattr  = (const float*)d_in[2];
    const float* lpW = (const float*)d_in[3];
    const float* lpb = (const float*)d_in[4];
    const float* tW  = (const float*)d_in[5];
    const float* tb  = (const float*)d_in[6];
    const float* eW1 = (const float*)d_in[7];
    const float* eb1 = (const float*)d_in[8];
    const float* eW2 = (const float*)d_in[9];
    const float* eb2 = (const float*)d_in[10];
    const float* c1W = (const float*)d_in[11];
    const float* c1B = (const float*)d_in[12];
    const float* c1R = (const float*)d_in[13];
    const float* c1b = (const float*)d_in[14];
    const float* c2W = (const float*)d_in[15];
    const float* c2B = (const float*)d_in[16];
    const float* c2R = (const float*)d_in[17];
    const float* c2b = (const float*)d_in[18];
    const float* oW  = (const float*)d_in[19];
    const float* ob  = (const float*)d_in[20];

    int N = in_sizes[0] / 24;
    int E = in_sizes[1] / 2;
    const int* srcA = eidx;
    const int* dstA = eidx + E;

    char* wsb = (char*)d_ws;
    size_t off = 0;
    auto alloc = [&](size_t bytes) {
        off = (off + 255) & ~(size_t)255;
        void* p = wsb + off;
        off += bytes;
        return p;
    };
    unsigned short* Y     = (unsigned short*)alloc((size_t)17 * N * 24 * 2);
    unsigned short* msg16 = (unsigned short*)alloc((size_t)E * 32 * 2);
    unsigned short* er_s  = (unsigned short*)alloc((size_t)E * 16 * 2);
    float* root = (float*)alloc((size_t)N * 24 * 4);
    float* x16  = (float*)alloc((size_t)N * 16 * 4);
    float* x24a = (float*)alloc((size_t)N * 24 * 4);
    float* x24b = (float*)alloc((size_t)N * 24 * 4);
    int* ibase  = (int*)alloc(((size_t)2 * N + 2) * 4);  // cntS | cntD | cursS | cursD (zeroed)
    int* cntS = ibase;
    int* cntD = ibase + N;
    int* cursS = ibase + 2 * N;
    int* cursD = ibase + 2 * N + 1;
    int* offsS = (int*)alloc((size_t)N * 4);
    int* offsD = (int*)alloc((size_t)N * 4);
    int* jS    = (int*)alloc((size_t)E * 4);
    int* jD    = (int*)alloc((size_t)E * 4);
    uint2* spq = (uint2*)alloc((size_t)E * 8);

    dim3 blk(BS);
    int nb_nodes = (N + BS - 1) / BS;
    int nb_edges = (E + BS - 1) / BS;
    int nb_msg   = (3 * E + BS - 1) / BS;
    int nb_gath  = ((size_t)N * 64 + BS - 1) / BS;     // one wave per node
    int nb_ypair = (N + BS * 2 - 1) / (BS * 2);        // 2 nodes per thread
    dim3 ygrid(nb_ypair, 18);

    hipMemsetAsync(ibase, 0, (2 * (size_t)N + 2) * 4, stream);

    prep_kernel<<<nb_nodes, blk, 0, stream>>>(x_feat, lpW, lpb, tW, tb, x16, N);

    degjj_kernel<<<nb_edges, blk, 0, stream>>>(srcA, dstA, cntS, cntD, jS, jD, E);
    offsets2_kernel<<<nb_nodes, blk, 0, stream>>>(cntS, cntD, offsS, offsD, cursS, cursD, N);
    er_fill_kernel<<<nb_edges, blk, 0, stream>>>(srcA, dstA, jS, jD, offsS, offsD,
                                                 eattr, eW1, eb1, eW2, eb2, spq, er_s, E);

    // ---- conv1 ----
    ynode_kernel<16><<<ygrid, blk, 0, stream>>>(x16, c1W, c1B, c1R, c1b, Y, root, N);
    msg_kernel<<<nb_msg, blk, 0, stream>>>(spq, er_s, Y, msg16, N, E);
    gather_kernel<<<nb_gath, blk, 0, stream>>>(msg16, offsD, cntD, root, x24a, N);

    // ---- conv2 ----
    ynode_kernel<24><<<ygrid, blk, 0, stream>>>(x24a, c2W, c2B, c2R, c2b, Y, root, N);
    msg_kernel<<<nb_msg, blk, 0, stream>>>(spq, er_s, Y, msg16, N, E);
    gather_kernel<<<nb_gath, blk, 0, stream>>>(msg16, offsD, cntD, root, x24b, N);

    head_kernel<<<nb_nodes, blk, 0, stream>>>(x24b, oW, ob, (float*)d_out, N);
}